// Round 13
// baseline (12052.624 us; speedup 1.0000x reference)
//
#include <hip/hip_runtime.h>

#define DH 512
#define TT 1024
#define BB 64
#define DT 64
#define RD 4   // ring depth (emergency fallback)
#define RG 32  // rows per batch-group

typedef _Float16 f16x8 __attribute__((ext_vector_type(8)));
typedef float f32x4 __attribute__((ext_vector_type(4)));

#define ATILE_HALVES   (64 * 65 * 8)
#define ATILE32_HALVES (64 * 33 * 8)

__device__ __forceinline__ f16x8 cload(const _Float16* p) {
  return *(const volatile f16x8*)p;
}
__device__ __forceinline__ void cstore(_Float16* p, f16x8 v) {
  *(volatile f16x8*)p = v;
}

// ---------------------------------------------------------------- precompute

__global__ __launch_bounds__(512) void eprime_kernel(
    const float* __restrict__ emb, const float* __restrict__ wx0,
    float* __restrict__ Ep)
{
  __shared__ float er[DH];
  const int e = blockIdx.x, j = threadIdx.x;
  er[j] = emb[(size_t)e * DH + j];
  __syncthreads();
  float acc = 0.f;
#pragma unroll 8
  for (int k = 0; k < DH; ++k) acc = fmaf(er[k], wx0[(size_t)k * DH + j], acc);
  Ep[(size_t)e * DH + j] = acc;
}

__global__ __launch_bounds__(512) void pack_kernel(
    const float* __restrict__ Ep, const float* __restrict__ wh0,
    const float* __restrict__ wx1, const float* __restrict__ wh1,
    const float* __restrict__ wx2, const float* __restrict__ wh2,
    const float* __restrict__ gamma, _Float16* __restrict__ dst)
{
  __shared__ float Tt[64][65];
  const int m = blockIdx.z, jt = blockIdx.x, kt = blockIdx.y;
  const float* src = (m == 0) ? Ep : (m == 1) ? wh0 : (m == 2) ? wx1
                   : (m == 3) ? wh1 : (m == 4) ? wx2 : wh2;
  const bool fold = (m == 2 || m == 4);
  const int tx = threadIdx.x & 63, ty = threadIdx.x >> 6;
#pragma unroll
  for (int i = 0; i < 8; ++i) {
    const int k = kt * 64 + ty * 8 + i;
    Tt[ty * 8 + i][tx] = src[(size_t)k * DH + jt * 64 + tx];
  }
  __syncthreads();
#pragma unroll
  for (int i = 0; i < 8; ++i) {
    const int j = jt * 64 + ty * 8 + i;
    const int k = kt * 64 + tx;
    float v = Tt[tx][ty * 8 + i];
    if (fold) v *= gamma[k];
    dst[((size_t)m * DH + j) * DH + k] = (_Float16)v;
  }
}

__global__ __launch_bounds__(512) void fold_kernel(
    const float* __restrict__ b0, const float* __restrict__ b1,
    const float* __restrict__ b2, const float* __restrict__ wx1,
    const float* __restrict__ wx2, const float* __restrict__ gamma,
    const float* __restrict__ beta, const float* __restrict__ clfw,
    const float* __restrict__ clfb,
    float* __restrict__ bfold, float* __restrict__ csum,
    float* __restrict__ clfwf, float* __restrict__ clfbf)
{
  const int j = threadIdx.x;
  if (blockIdx.x == 0) {
    bfold[j] = b0[j];
    float s1 = 0, s2 = 0, c1 = 0, c2 = 0;
    for (int k = 0; k < DH; ++k) {
      const float w1 = wx1[(size_t)k * DH + j], w2 = wx2[(size_t)k * DH + j];
      s1 += beta[k] * w1;  s2 += beta[k] * w2;
      c1 += gamma[k] * w1; c2 += gamma[k] * w2;
    }
    bfold[DH + j] = b1[j] + s1;
    bfold[2 * DH + j] = b2[j] + s2;
    csum[j] = c1; csum[DH + j] = c2;
  } else {
    for (int idx = j; idx < DH * DT; idx += 512) {
      const int k = idx >> 6, d = idx & 63;
      clfwf[idx] = gamma[k] * clfw[(size_t)k * DT + d];
    }
    if (j < DT) {
      float sb = clfb[j];
      for (int k = 0; k < DH; ++k) sb += beta[k] * clfw[(size_t)k * DT + j];
      clfbf[j] = sb;
    }
  }
}

// v_all[t][b][j] (fp16) = sum_e x[b][t][e] * E'[e][j];  one block per t.
__global__ __launch_bounds__(512, 1) void vgemm_kernel(
    const float* __restrict__ x, const _Float16* __restrict__ Bt,
    _Float16* __restrict__ v)
{
  const int t = blockIdx.x;
  const int tid = threadIdx.x, l = tid & 63, w = tid >> 6;
  __shared__ __align__(16) _Float16 A[ATILE_HALVES];
  {
    const int row = tid >> 3, part = tid & 7;
    const float4* sp = (const float4*)(x + ((size_t)row * TT + t) * DH);
#pragma unroll
    for (int i = 0; i < 8; ++i) {
      const int ks = i * 8 + part;
      const float4 a = sp[ks * 2], b = sp[ks * 2 + 1];
      f16x8 vv;
      vv[0] = (_Float16)a.x; vv[1] = (_Float16)a.y; vv[2] = (_Float16)a.z; vv[3] = (_Float16)a.w;
      vv[4] = (_Float16)b.x; vv[5] = (_Float16)b.y; vv[6] = (_Float16)b.z; vv[7] = (_Float16)b.w;
      *(f16x8*)(A + ((size_t)ks * 65 + row) * 8) = vv;
    }
  }
  __syncthreads();
  const int jb = w * 64;
  const int arowb = l & 15, g = l >> 4;
  f32x4 acc[4][4];
#pragma unroll
  for (int mf = 0; mf < 4; ++mf)
#pragma unroll
    for (int nf = 0; nf < 4; ++nf)
#pragma unroll
      for (int e = 0; e < 4; ++e) acc[mf][nf][e] = 0.f;
#pragma unroll
  for (int kk = 0; kk < 16; ++kk) {
    const int ks = kk * 4 + g;
    f16x8 am[4], bn[4];
#pragma unroll
    for (int mf = 0; mf < 4; ++mf)
      am[mf] = *(const f16x8*)(A + ((size_t)ks * 65 + mf * 16 + arowb) * 8);
#pragma unroll
    for (int nf = 0; nf < 4; ++nf)
      bn[nf] = *(const f16x8*)(Bt + (size_t)(jb + nf * 16 + arowb) * DH + kk * 32 + g * 8);
#pragma unroll
    for (int mf = 0; mf < 4; ++mf)
#pragma unroll
      for (int nf = 0; nf < 4; ++nf)
        acc[mf][nf] = __builtin_amdgcn_mfma_f32_16x16x32_f16(am[mf], bn[nf], acc[mf][nf], 0, 0, 0);
  }
#pragma unroll
  for (int mf = 0; mf < 4; ++mf)
#pragma unroll
    for (int nf = 0; nf < 4; ++nf)
#pragma unroll
      for (int i = 0; i < 4; ++i) {
        const int r = mf * 16 + (l >> 4) * 4 + i;
        const int j = jb + nf * 16 + (l & 15);
        v[((size_t)t * BB + r) * DH + j] = (_Float16)acc[mf][nf][i];
      }
}

// ---------------------------------------------------------------- staging

__device__ __forceinline__ void stage_h32(_Float16* __restrict__ A,
                                          const _Float16* __restrict__ src64,
                                          int rbase, float* muA, float* rsA,
                                          bool stats, int tid)
{
  const int row = tid >> 4, part = tid & 15;
  const _Float16* sp = src64 + (size_t)(rbase + row) * DH;
  f16x8 v[4];
#pragma unroll
  for (int i = 0; i < 4; ++i) v[i] = cload(sp + (size_t)(i * 16 + part) * 8);
  float sum = 0.f, sq = 0.f;
#pragma unroll
  for (int i = 0; i < 4; ++i) {
    const int ks = i * 16 + part;
    *(f16x8*)(A + ((size_t)ks * 33 + row) * 8) = v[i];
    if (stats) {
#pragma unroll
      for (int e = 0; e < 8; ++e) { const float f = (float)v[i][e]; sum += f; sq += f * f; }
    }
  }
  if (stats) {
    sum += __shfl_xor(sum, 1); sq += __shfl_xor(sq, 1);
    sum += __shfl_xor(sum, 2); sq += __shfl_xor(sq, 2);
    sum += __shfl_xor(sum, 4); sq += __shfl_xor(sq, 4);
    sum += __shfl_xor(sum, 8); sq += __shfl_xor(sq, 8);
    if (part == 0) {
      const float mu = sum * (1.f / DH);
      const float var = sq * (1.f / DH) - mu * mu;
      muA[row] = mu; rsA[row] = rsqrtf(var + 1e-5f);
    }
  }
}

__device__ __forceinline__ void stage_x32(_Float16* __restrict__ A,
                                          const float* __restrict__ inputs,
                                          int rbase, int t, int tid)
{
  const int row = tid >> 4, part = tid & 15;
  const float4* sp = (const float4*)(inputs + ((size_t)(rbase + row) * TT + t) * DH);
#pragma unroll
  for (int i = 0; i < 4; ++i) {
    const int ks = i * 16 + part;
    const float4 a = sp[ks * 2], b = sp[ks * 2 + 1];
    f16x8 vv;
    vv[0] = (_Float16)a.x; vv[1] = (_Float16)a.y; vv[2] = (_Float16)a.z; vv[3] = (_Float16)a.w;
    vv[4] = (_Float16)b.x; vv[5] = (_Float16)b.y; vv[6] = (_Float16)b.z; vv[7] = (_Float16)b.w;
    *(f16x8*)(A + ((size_t)ks * 33 + row) * 8) = vv;
  }
}

__device__ __forceinline__ void stage_h_coh(_Float16* __restrict__ A,
                                            const _Float16* __restrict__ src,
                                            float* muA, float* rsA, bool stats,
                                            int tid)
{
  const int row = tid >> 3, part = tid & 7;
  const _Float16* sp = src + (size_t)row * DH;
  f16x8 v[8];
#pragma unroll
  for (int i = 0; i < 8; ++i) v[i] = cload(sp + (size_t)(i * 8 + part) * 8);
  float sum = 0.f, sq = 0.f;
#pragma unroll
  for (int i = 0; i < 8; ++i) {
    const int ks = i * 8 + part;
    *(f16x8*)(A + ((size_t)ks * 65 + row) * 8) = v[i];
    if (stats) {
#pragma unroll
      for (int e = 0; e < 8; ++e) { const float f = (float)v[i][e]; sum += f; sq += f * f; }
    }
  }
  if (stats) {
    sum += __shfl_xor(sum, 1); sq += __shfl_xor(sq, 1);
    sum += __shfl_xor(sum, 2); sq += __shfl_xor(sq, 2);
    sum += __shfl_xor(sum, 4); sq += __shfl_xor(sq, 4);
    if (part == 0) {
      const float mu = sum * (1.f / DH);
      const float var = sq * (1.f / DH) - mu * mu;
      muA[row] = mu; rsA[row] = rsqrtf(var + 1e-5f);
    }
  }
}

__device__ __forceinline__ void stage_x64(_Float16* __restrict__ A,
                                          const float* __restrict__ inputs,
                                          int t, int tid)
{
  const int row = tid >> 3, part = tid & 7;
  const float4* sp = (const float4*)(inputs + ((size_t)row * TT + t) * DH);
#pragma unroll
  for (int i = 0; i < 8; ++i) {
    const int ks = i * 8 + part;
    const float4 a = sp[ks * 2], b = sp[ks * 2 + 1];
    f16x8 vv;
    vv[0] = (_Float16)a.x; vv[1] = (_Float16)a.y; vv[2] = (_Float16)a.z; vv[3] = (_Float16)a.w;
    vv[4] = (_Float16)b.x; vv[5] = (_Float16)b.y; vv[6] = (_Float16)b.z; vv[7] = (_Float16)b.w;
    *(f16x8*)(A + ((size_t)ks * 65 + row) * 8) = vv;
  }
}

__device__ __forceinline__ void spin_mask(unsigned* p, unsigned tgt) {
  while (true) {
    bool mine = true;
    if (p) mine = (__hip_atomic_load(p, __ATOMIC_RELAXED, __HIP_MEMORY_SCOPE_AGENT) >= tgt);
    if (__all(mine)) break;
    __builtin_amdgcn_s_sleep(1);
  }
}

// ---------------------------------------------------------------- main RNN (r13)

// 20 blocks: 12 H (recurrence, Wh only, own h-half LDS-local, sibling fan-in 1)
//          + 8 X (LN + gamma*Wx for layers 1,2; off the critical cycle).
__global__ __launch_bounds__(512, 1) void rnn13_kernel(
    const _Float16* __restrict__ v_all, const _Float16* __restrict__ packB,
    const float* __restrict__ bfold, const float* __restrict__ csum,
    _Float16* __restrict__ h_base, _Float16* __restrict__ xp_base,
    unsigned* __restrict__ harr, unsigned* __restrict__ xflg)
{
  const int bid = blockIdx.x;
  const int tid = threadIdx.x;
  const int l = tid & 63, w = tid >> 6;
  const int g = l >> 4;

  __shared__ __align__(16) _Float16 AT[ATILE32_HALVES];   // [64 ksub][33][8]
  __shared__ __align__(16) _Float16 xpl[32 * 264];
  __shared__ __align__(16) _Float16 hout[32 * 264];
  __shared__ float muS[RG], rsS[RG];

  if (bid < 12) {
    // ================= H role =================
    const int s = bid >> 2, rg = (bid >> 1) & 1, half = bid & 1;
    const int rbase = rg * RG, cbase = half * 256;
    const int scb = (1 - half) * 256;

    f16x8 Bh[16][2];
    {
      const int colb = cbase + w * 32 + (l & 15);
      const _Float16* pw = packB + ((size_t)(s * 2 + 1) * DH + colb) * DH + (size_t)(l >> 4) * 8;
#pragma unroll
      for (int kk = 0; kk < 16; ++kk) {
        Bh[kk][0] = *(const f16x8*)(pw + kk * 32);
        Bh[kk][1] = *(const f16x8*)(pw + (size_t)16 * DH + kk * 32);
      }
    }
    const float b0_ = bfold[s * DH + cbase + w * 32 + (l & 15)];
    const float b1_ = bfold[s * DH + cbase + w * 32 + 16 + (l & 15)];
    const int sidx = s * 4 + rg * 2 + (1 - half);
    const int myidx = s * 4 + rg * 2 + half;
    const int xidx = (s >= 1) ? ((s - 1) * 4 + rg * 2 + half) : -1;

    for (int t = 0; t < TT; ++t) {
      // poll (wave0): lane0 sibling h(t-1), lane1 xpart(t)
      if (w == 0) {
        unsigned* p = nullptr; unsigned tgt = 0;
        if (l == 0 && t >= 1)       { p = harr + (size_t)sidx * 16; tgt = (unsigned)t; }
        else if (l == 1 && xidx >= 0) { p = xflg + (size_t)xidx * 16; tgt = (unsigned)(t + 1); }
        spin_mask(p, tgt);
      }
      // own-half-K MFMA (local LDS data; overlaps wave0's poll)
      f32x4 acc[2][2];
#pragma unroll
      for (int mf = 0; mf < 2; ++mf)
#pragma unroll
        for (int e = 0; e < 4; ++e) { acc[mf][0][e] = 0.f; acc[mf][1][e] = 0.f; }
      if (t >= 1) {
        const int k0 = half * 8;
#pragma unroll
        for (int kq = 0; kq < 8; ++kq) {
          const int kk = k0 + kq;
          const int ks = kk * 4 + g;
#pragma unroll
          for (int mf = 0; mf < 2; ++mf) {
            const f16x8 a = *(const f16x8*)(AT + ((size_t)ks * 33 + mf * 16 + (l & 15)) * 8);
            acc[mf][0] = __builtin_amdgcn_mfma_f32_16x16x32_f16(a, Bh[kk][0], acc[mf][0], 0, 0, 0);
            acc[mf][1] = __builtin_amdgcn_mfma_f32_16x16x32_f16(a, Bh[kk][1], acc[mf][1], 0, 0, 0);
          }
        }
      }
      __syncthreads();   // B1: polls satisfied

      // stage sibling half (16KB, volatile) + xpart (16KB)
      {
        const int row = tid >> 4, part = tid & 15;
        if (t >= 1) {
          const _Float16* sp = h_base + ((size_t)s * TT + (t - 1)) * BB * DH
                               + (size_t)(rbase + row) * DH + scb + part * 16;
          const f16x8 v0 = cload(sp), v1 = cload(sp + 8);
          const int ks0 = (scb >> 3) + part * 2;
          *(f16x8*)(AT + ((size_t)ks0 * 33 + row) * 8) = v0;
          *(f16x8*)(AT + ((size_t)(ks0 + 1) * 33 + row) * 8) = v1;
        }
        if (s == 0) {
          const _Float16* xs = v_all + (size_t)t * BB * DH
                               + (size_t)(rbase + row) * DH + cbase + part * 16;
          *(f16x8*)(xpl + (size_t)row * 264 + part * 16)     = *(const f16x8*)xs;
          *(f16x8*)(xpl + (size_t)row * 264 + part * 16 + 8) = *(const f16x8*)(xs + 8);
        } else {
          const _Float16* xs = xp_base + ((size_t)(s - 1) * TT + t) * BB * DH
                               + (size_t)(rbase + row) * DH + cbase + part * 16;
          *(f16x8*)(xpl + (size_t)row * 264 + part * 16)     = cload(xs);
          *(f16x8*)(xpl + (size_t)row * 264 + part * 16 + 8) = cload(xs + 8);
        }
      }
      __syncthreads();   // B2: staging visible

      // sibling-half-K MFMA
      if (t >= 1) {
        const int k0 = (1 - half) * 8;
#pragma unroll
        for (int kq = 0; kq < 8; ++kq) {
          const int kk = k0 + kq;
          const int ks = kk * 4 + g;
#pragma unroll
          for (int mf = 0; mf < 2; ++mf) {
            const f16x8 a = *(const f16x8*)(AT + ((size_t)ks * 33 + mf * 16 + (l & 15)) * 8);
            acc[mf][0] = __builtin_amdgcn_mfma_f32_16x16x32_f16(a, Bh[kk][0], acc[mf][0], 0, 0, 0);
            acc[mf][1] = __builtin_amdgcn_mfma_f32_16x16x32_f16(a, Bh[kk][1], acc[mf][1], 0, 0, 0);
          }
        }
      }

      // epilogue: h = tanh(acc + xpart + b); own half -> local AT + hout
      {
        const int coll = w * 32 + (l & 15);
#pragma unroll
        for (int mf = 0; mf < 2; ++mf)
#pragma unroll
          for (int nf = 0; nf < 2; ++nf)
#pragma unroll
            for (int i = 0; i < 4; ++i) {
              const int r = mf * 16 + g * 4 + i;
              const int cl = coll + nf * 16;
              const float p = acc[mf][nf][i] + (float)xpl[(size_t)r * 264 + cl]
                              + (nf ? b1_ : b0_);
              const _Float16 hv = (_Float16)tanhf(p);
              hout[(size_t)r * 264 + cl] = hv;
              const int kg = cbase + cl;
              AT[((size_t)(kg >> 3) * 33 + r) * 8 + (kg & 7)] = hv;
            }
      }
      __syncthreads();   // B3: hout + local AT writes done

      // publish own 32x256 slice (write-through to LLC)
      {
        const int row = tid >> 4, part = tid & 15;
        _Float16* dst = h_base + ((size_t)s * TT + t) * BB * DH
                        + (size_t)(rbase + row) * DH + cbase + part * 16;
        cstore(dst,     *(const f16x8*)(hout + (size_t)row * 264 + part * 16));
        cstore(dst + 8, *(const f16x8*)(hout + (size_t)row * 264 + part * 16 + 8));
      }
      __syncthreads();   // B4: vmcnt drained -> LLC visible
      if (tid == 0)
        __hip_atomic_store(harr + (size_t)myidx * 16, (unsigned)(t + 1),
                           __ATOMIC_RELAXED, __HIP_MEMORY_SCOPE_AGENT);
    }
  } else {
    // ================= X role =================
    const int e = bid - 12;
    const int s = 1 + (e >> 2), rg = (e >> 1) & 1, half = e & 1;
    const int rbase = rg * RG, cbase = half * 256;

    f16x8 Bx[16][2];
    {
      const int colb = cbase + w * 32 + (l & 15);
      const _Float16* pw = packB + ((size_t)(s * 2) * DH + colb) * DH + (size_t)(l >> 4) * 8;
#pragma unroll
      for (int kk = 0; kk < 16; ++kk) {
        Bx[kk][0] = *(const f16x8*)(pw + kk * 32);
        Bx[kk][1] = *(const f16x8*)(pw + (size_t)16 * DH + kk * 32);
      }
    }
    const float cs0 = csum[(s - 1) * DH + cbase + w * 32 + (l & 15)];
    const float cs1 = csum[(s - 1) * DH + cbase + w * 32 + 16 + (l & 15)];
    const int i0 = (s - 1) * 4 + rg * 2 + 0;
    const int i1 = (s - 1) * 4 + rg * 2 + 1;
    const int myx = (s - 1) * 4 + rg * 2 + half;

    for (int t = 0; t < TT; ++t) {
      if (w == 0) {
        unsigned* p = nullptr; unsigned tgt = 0;
        if (l == 0)      { p = harr + (size_t)i0 * 16; tgt = (unsigned)(t + 1); }
        else if (l == 1) { p = harr + (size_t)i1 * 16; tgt = (unsigned)(t + 1); }
        spin_mask(p, tgt);
      }
      __syncthreads();
      stage_h32(AT, h_base + ((size_t)(s - 1) * TT + t) * BB * DH, rbase,
                muS, rsS, true, tid);
      __syncthreads();

      f32x4 acc[2][2];
#pragma unroll
      for (int mf = 0; mf < 2; ++mf)
#pragma unroll
        for (int ee = 0; ee < 4; ++ee) { acc[mf][0][ee] = 0.f; acc[mf][1][ee] = 0.f; }
#pragma unroll
      for (int kk = 0; kk < 16; ++kk) {
        const int ks = kk * 4 + g;
#pragma unroll
        for (int mf = 0; mf < 2; ++mf) {
          const f16x8 a = *(const f16x8*)(AT + ((size_t)ks * 33 + mf * 16 + (l & 15)) * 8);
          acc[mf][0] = __builtin_amdgcn_mfma_f32_16x16x32_f16(a, Bx[kk][0], acc[mf][0], 0, 0, 0);
          acc[mf][1] = __builtin_amdgcn_mfma_f32_16x16x32_f16(a, Bx[kk][1], acc[mf][1], 0, 0, 0);
        }
      }

      {
        const int coll = w * 32 + (l & 15);
#pragma unroll
        for (int mf = 0; mf < 2; ++mf)
#pragma unroll
          for (int nf = 0; nf < 2; ++nf)
#pragma unroll
            for (int i = 0; i < 4; ++i) {
              const int r = mf * 16 + g * 4 + i;
              const float val = rsS[r] * (acc[mf][nf][i] - muS[r] * (nf ? cs1 : cs0));
              hout[(size_t)r * 264 + coll + nf * 16] = (_Float16)val;
            }
      }
      __syncthreads();
      {
        const int row = tid >> 4, part = tid & 15;
        _Float16* dst = xp_base + ((size_t)(s - 1) * TT + t) * BB * DH
                        + (size_t)(rbase + row) * DH + cbase + part * 16;
        cstore(dst,     *(const f16x8*)(hout + (size_t)row * 264 + part * 16));
        cstore(dst + 8, *(const f16x8*)(hout + (size_t)row * 264 + part * 16 + 8));
      }
      __syncthreads();
      if (tid == 0)
        __hip_atomic_store(xflg + (size_t)myx * 16, (unsigned)(t + 1),
                           __ATOMIC_RELAXED, __HIP_MEMORY_SCOPE_AGENT);
    }
  }
}

// ---------------------------------------------------- r12 fallback (champion)

__global__ __launch_bounds__(512, 1) void rnn12_kernel(
    const float* __restrict__ inputs, const _Float16* __restrict__ v_all,
    const int use_v, const _Float16* __restrict__ packB,
    const float* __restrict__ bfold, const float* __restrict__ csum,
    _Float16* __restrict__ h_base, unsigned* __restrict__ arr)
{
  const int bid = blockIdx.x;
  const int s = bid >> 4, g2 = (bid >> 3) & 1, c = bid & 7;
  const int rbase = g2 * RG;
  const int tid = threadIdx.x;
  const int l = tid & 63, w = tid >> 6;
  const int mg = w >> 2, ng = w & 3;

  __shared__ __align__(16) _Float16 A1[ATILE32_HALVES];
  __shared__ __align__(16) _Float16 A2[ATILE32_HALVES];
  __shared__ __align__(16) _Float16 hout[RG][72];
  __shared__ float muS[RG], rsS[RG];

  const bool sx = (s == 0);
  const bool havev = (use_v != 0);
  const bool needX = (!sx || !havev);

  const int colbase = c * 64 + ng * 16 + (l & 15);
  const int kbase = (l >> 4) * 8;
  f16x8 Bx[16], Bh[16];
  {
    const _Float16* ph = packB + ((size_t)(s * 2 + 1) * DH + colbase) * DH + kbase;
#pragma unroll
    for (int kk = 0; kk < 16; ++kk) Bh[kk] = *(const f16x8*)(ph + kk * 32);
  }
  if (needX) {
    const _Float16* px = packB + ((size_t)(s * 2 + 0) * DH + colbase) * DH + kbase;
#pragma unroll
    for (int kk = 0; kk < 16; ++kk) Bx[kk] = *(const f16x8*)(px + kk * 32);
  }

  const float b_j = bfold[s * DH + colbase];
  const float cs_j = (s > 0) ? csum[(s - 1) * DH + colbase] : 0.f;
  const int g = l >> 4;
  const int fbase = (s * 2 + g2) * 8;
  const int ubase = ((s - 1) * 2 + g2) * 8;

  for (int t = 0; t < TT; ++t) {
    _Float16 vp[4];
    if (sx && havev) {
      const _Float16* vb = v_all + (size_t)t * BB * DH + colbase;
      const int rb = rbase + mg * 16 + (l >> 4) * 4;
#pragma unroll
      for (int i = 0; i < 4; ++i) vp[i] = vb[(size_t)(rb + i) * DH];
    }

    if (w == 0) {
      unsigned* p = nullptr; unsigned tgt = 0;
      if (l < 8 && t >= 1) { p = arr + (fbase + l) * 16; tgt = (unsigned)t; }
      spin_mask(p, tgt);
    }
    __syncthreads();

    if (t >= 1)
      stage_h32(A2, h_base + ((size_t)s * TT + (t - 1)) * BB * DH, rbase,
                nullptr, nullptr, false, tid);
    __syncthreads();

    f32x4 accX, accH;
#pragma unroll
    for (int e = 0; e < 4; ++e) { accX[e] = 0.f; accH[e] = 0.f; }
    const int arow = mg * 16 + (l & 15);
    if (t >= 1) {
#pragma unroll
      for (int kk = 0; kk < 16; ++kk) {
        const int ks = kk * 4 + g;
        const f16x8 aH = *(const f16x8*)(A2 + ((size_t)ks * 33 + arow) * 8);
        accH = __builtin_amdgcn_mfma_f32_16x16x32_f16(aH, Bh[kk], accH, 0, 0, 0);
      }
    }

    if (s > 0) {
      if (w == 0) {
        unsigned* p = (l < 8) ? (arr + (ubase + l) * 16) : nullptr;
        spin_mask(p, (unsigned)(t + 1));
      }
      __syncthreads();
      stage_h32(A1, h_base + ((size_t)(s - 1) * TT + t) * BB * DH, rbase,
                muS, rsS, true, tid);
      __syncthreads();
    } else if (!havev) {
      stage_x32(A1, inputs, rbase, t, tid);
      __syncthreads();
    }

    if (needX) {
#pragma unroll
      for (int kk = 0; kk < 16; ++kk) {
        const int ks = kk * 4 + g;
        const f16x8 aX = *(const f16x8*)(A1 + ((size_t)ks * 33 + arow) * 8);
        accX = __builtin_amdgcn_mfma_f32_16x16x32_f16(aX, Bx[kk], accX, 0, 0, 0);
      }
    }

    const int jl = ng * 16 + (l & 15);
#pragma unroll
    for (int i = 0; i < 4; ++i) {
      const int r = mg * 16 + (l >> 4) * 4 + i;
      float p;
      if (sx) {
        const float v0 = havev ? (float)vp[i] : accX[i];
        p = v0 + accH[i] + b_j;
      } else {
        p = rsS[r] * (accX[i] - muS[r] * cs_j) + accH[i] + b_j;
      }
      hout[r][jl] = (_Float16)tanhf(p);
    }
    __syncthreads();

    if (tid < 256) {
      _Float16* dst = h_base + ((size_t)s * TT + t) * BB * DH;
      const int row = tid >> 3, ch = tid & 7;
      const f16x8 hv = *(const f16x8*)(&hout[row][ch * 8]);
      cstore(dst + (size_t)(rbase + row) * DH + c * 64 + ch * 8, hv);
    }
    __syncthreads();
    if (tid == 0)
      __hip_atomic_store(arr + (fbase + c) * 16, (unsigned)(t + 1),
                         __ATOMIC_RELAXED, __HIP_MEMORY_SCOPE_AGENT);
  }
}

// ------------------------------------------------- emergency ring fallback

__global__ __launch_bounds__(512, 1) void rnn_ring_kernel(
    const float* __restrict__ inputs, const _Float16* __restrict__ v_all,
    const int use_v, const _Float16* __restrict__ packB,
    const float* __restrict__ bfold, const float* __restrict__ csum,
    _Float16* __restrict__ h_base, unsigned* __restrict__ arr,
    unsigned* __restrict__ cons)
{
  const int bid = blockIdx.x;
  const int s = bid >> 3, c = bid & 7;
  const int tid = threadIdx.x;
  const int l = tid & 63, w = tid >> 6;
  const int mg = w >> 2, ng = w & 3;

  __shared__ __align__(16) _Float16 A1[ATILE_HALVES];
  __shared__ __align__(16) _Float16 A2[ATILE_HALVES];
  __shared__ __align__(16) _Float16 hout[64][72];
  __shared__ float muS[64], rsS[64];

  const bool sx = (s == 0);
  const bool havev = (use_v != 0);
  const bool needX = (!sx || !havev);

  const int colbase = c * 64 + ng * 16 + (l & 15);
  const int kbase = (l >> 4) * 8;
  f16x8 Bx[16], Bh[16];
  {
    const _Float16* ph = packB + ((size_t)(s * 2 + 1) * DH + colbase) * DH + kbase;
#pragma unroll
    for (int kk = 0; kk < 16; ++kk) Bh[kk] = *(const f16x8*)(ph + kk * 32);
  }
  if (needX) {
    const _Float16* px = packB + ((size_t)(s * 2 + 0) * DH + colbase) * DH + kbase;
#pragma unroll
    for (int kk = 0; kk < 16; ++kk) Bx[kk] = *(const f16x8*)(px + kk * 32);
  }

  const float b_j = bfold[s * DH + colbase];
  const float cs_j = (s > 0) ? csum[(s - 1) * DH + colbase] : 0.f;
  const int g = l >> 4;

  for (int t = 0; t < TT; ++t) {
    if (w == 0) {
      unsigned* p = nullptr; unsigned tgt = 0;
      if (l < 8) {
        if (t >= 1) { p = arr + (s * 8 + l) * 16; tgt = (unsigned)t; }
      } else if (l >= 16 && l < 24 && s < 2 && t >= RD) {
        p = cons + (s * 8 + (l - 16)) * 16; tgt = (unsigned)(t - RD + 1);
      }
      spin_mask(p, tgt);
    }
    __syncthreads();
    if (t >= 1)
      stage_h_coh(A2, h_base + (size_t)(s * RD + ((t - 1) & (RD - 1))) * BB * DH,
                  nullptr, nullptr, false, tid);
    __syncthreads();

    f32x4 accX[2], accH[2];
#pragma unroll
    for (int mf = 0; mf < 2; ++mf)
#pragma unroll
      for (int e = 0; e < 4; ++e) { accX[mf][e] = 0.f; accH[mf][e] = 0.f; }

    if (t >= 1) {
#pragma unroll
      for (int kk = 0; kk < 16; ++kk) {
        const int ks = kk * 4 + g;
#pragma unroll
        for (int mf = 0; mf < 2; ++mf) {
          const int arow = mg * 32 + mf * 16 + (l & 15);
          const f16x8 aH = *(const f16x8*)(A2 + ((size_t)ks * 65 + arow) * 8);
          accH[mf] = __builtin_amdgcn_mfma_f32_16x16x32_f16(aH, Bh[kk], accH[mf], 0, 0, 0);
        }
      }
    }

    if (s > 0) {
      if (w == 0) {
        unsigned* p = (l < 8) ? (arr + ((s - 1) * 8 + l) * 16) : nullptr;
        spin_mask(p, (unsigned)(t + 1));
      }
      __syncthreads();
      stage_h_coh(A1, h_base + (size_t)((s - 1) * RD + (t & (RD - 1))) * BB * DH,
                  muS, rsS, true, tid);
      __syncthreads();
      if (tid == 0)
        __hip_atomic_store(cons + ((s - 1) * 8 + c) * 16, (unsigned)(t + 1),
                           __ATOMIC_RELAXED, __HIP_MEMORY_SCOPE_AGENT);
    } else if (!havev) {
      stage_x64(A1, inputs, t, tid);
      __syncthreads();
    }

    if (needX) {
#pragma unroll
      for (int kk = 0; kk < 16; ++kk) {
        const int ks = kk * 4 + g;
#pragma unroll
        for (int mf = 0; mf < 2; ++mf) {
          const int arow = mg * 32 + mf * 16 + (l & 15);
          const f16x8 aX = *(const f16x8*)(A1 + ((size_t)ks * 65 + arow) * 8);
          accX[mf] = __builtin_amdgcn_mfma_f32_16x16x32_f16(aX, Bx[kk], accX[mf], 0, 0, 0);
        }
      }
    }

    const int jl = ng * 16 + (l & 15);
#pragma unroll
    for (int mf = 0; mf < 2; ++mf)
#pragma unroll
      for (int i = 0; i < 4; ++i) {
        const int r = mg * 32 + mf * 16 + (l >> 4) * 4 + i;
        float p;
        if (sx) {
          float v0;
          if (havev) v0 = (float)v_all[((size_t)t * BB + r) * DH + c * 64 + jl];
          else       v0 = accX[mf][i];
          p = v0 + accH[mf][i] + b_j;
        } else {
          p = rsS[r] * (accX[mf][i] - muS[r] * cs_j) + accH[mf][i] + b_j;
        }
        hout[r][jl] = (_Float16)tanhf(p);
      }
    __syncthreads();
    {
      _Float16* dst = h_base + (size_t)(s * RD + (t & (RD - 1))) * BB * DH;
      const int row = tid >> 3, ch = tid & 7;
      const f16x8 hv = *(const f16x8*)(&hout[row][ch * 8]);
      cstore(dst + (size_t)row * DH + c * 64 + ch * 8, hv);
    }
    __syncthreads();
    if (tid == 0)
      __hip_atomic_store(arr + (s * 8 + c) * 16, (unsigned)(t + 1),
                         __ATOMIC_RELAXED, __HIP_MEMORY_SCOPE_AGENT);
  }
}

// ---------------------------------------------------------------- classifier

__global__ __launch_bounds__(64) void clf_kernel(
    const _Float16* __restrict__ h2, const float* __restrict__ clfwf,
    const float* __restrict__ clfbf, float* __restrict__ out)
{
  const int b = blockIdx.x, d = threadIdx.x;
  __shared__ float o2[DH];
  const _Float16* hrow = h2 + (size_t)b * DH;
  float sum = 0.f, sq = 0.f;
#pragma unroll
  for (int i = 0; i < 8; ++i) {
    const float v = (float)hrow[d * 8 + i];
    sum += v; sq += v * v;
  }
#pragma unroll
  for (int off = 32; off; off >>= 1) { sum += __shfl_xor(sum, off); sq += __shfl_xor(sq, off); }
  const float mu = sum * (1.f / DH);
  const float rs = rsqrtf(sq * (1.f / DH) - mu * mu + 1e-5f);
#pragma unroll
  for (int i = 0; i < 8; ++i) o2[d * 8 + i] = ((float)hrow[d * 8 + i] - mu) * rs;
  __syncthreads();
  float acc = clfbf[d];
#pragma unroll 8
  for (int k = 0; k < DH; ++k) acc = fmaf(o2[k], clfwf[k * DT + d], acc);
  float mx = acc;
#pragma unroll
  for (int off = 32; off; off >>= 1) mx = fmaxf(mx, __shfl_xor(mx, off));
  const float e = expf(acc - mx);
  float ss = e;
#pragma unroll
  for (int off = 32; off; off >>= 1) ss += __shfl_xor(ss, off);
  out[(size_t)b * DT + d] = e / ss;
}

// ---------------------------------------------------------------- launch

extern "C" void kernel_launch(void* const* d_in, const int* in_sizes, int n_in,
                              void* d_out, int out_size, void* d_ws, size_t ws_size,
                              hipStream_t stream) {
  const float* inputs = (const float*)d_in[0];
  const float* emb    = (const float*)d_in[1];
  const float* wx0    = (const float*)d_in[2];
  const float* wh0    = (const float*)d_in[3];
  const float* b0     = (const float*)d_in[4];
  const float* wx1    = (const float*)d_in[5];
  const float* wh1    = (const float*)d_in[6];
  const float* b1     = (const float*)d_in[7];
  const float* wx2    = (const float*)d_in[8];
  const float* wh2    = (const float*)d_in[9];
  const float* b2     = (const float*)d_in[10];
  const float* gamma  = (const float*)d_in[11];
  const float* beta   = (const float*)d_in[12];
  const float* clfw   = (const float*)d_in[13];
  const float* clfb   = (const float*)d_in[14];
  float* out = (float*)d_out;

  char* ws = (char*)d_ws;
  size_t off = 0;
  float*    Ep    = (float*)(ws + off);    off += (size_t)DH * DH * 4;
  _Float16* packB = (_Float16*)(ws + off); off += (size_t)6 * DH * DH * 2;
  float*    bfold = (float*)(ws + off);    off += (size_t)3 * DH * 4;
  float*    csumP = (float*)(ws + off);    off += (size_t)2 * DH * 4;
  float*    clfwf = (float*)(ws + off);    off += (size_t)DH * DT * 4;
  float*    clfbf = (float*)(ws + off);    off += 256;
  unsigned* flags = (unsigned*)(ws + off); off += (size_t)2048 * 4;   // 8KB flag pool
  off = (off + 255) & ~(size_t)255;
  _Float16* h_base = (_Float16*)(ws + off);

  const size_t H_BYTES  = (size_t)3 * TT * BB * DH * 2;   // 192MB
  const size_t XP_BYTES = (size_t)2 * TT * BB * DH * 2;   // 128MB
  const size_t V_BYTES  = (size_t)TT * BB * DH * 2;       //  64MB
  const size_t ring_h_bytes = (size_t)3 * RD * BB * DH * 2;

  const int mode13 = (ws_size >= off + H_BYTES + XP_BYTES + V_BYTES) ? 1 : 0;
  const int mode12 = (!mode13 && ws_size >= off + H_BYTES + V_BYTES) ? 1 : 0;

  (void)hipMemsetAsync(flags, 0, (size_t)2048 * 4, stream);
  hipLaunchKernelGGL(eprime_kernel, dim3(DH), dim3(512), 0, stream, emb, wx0, Ep);
  hipLaunchKernelGGL(pack_kernel, dim3(8, 8, 6), dim3(512), 0, stream,
                     Ep, wh0, wx1, wh1, wx2, wh2, gamma, packB);
  hipLaunchKernelGGL(fold_kernel, dim3(2), dim3(512), 0, stream,
                     b0, b1, b2, wx1, wx2, gamma, beta, clfw, clfb,
                     bfold, csumP, clfwf, clfbf);

  if (mode13) {
    _Float16* xp_base = (_Float16*)((char*)h_base + H_BYTES);
    _Float16* v_all   = (_Float16*)((char*)h_base + H_BYTES + XP_BYTES);
    unsigned* harr = flags;
    unsigned* xflg = flags + 12 * 16;
    hipLaunchKernelGGL(vgemm_kernel, dim3(TT), dim3(512), 0, stream,
                       inputs, packB, v_all);
    hipLaunchKernelGGL(rnn13_kernel, dim3(20), dim3(512), 0, stream,
                       v_all, packB, bfold, csumP, h_base, xp_base, harr, xflg);
    const _Float16* h2fin = h_base + ((size_t)2 * TT + (TT - 1)) * BB * DH;
    hipLaunchKernelGGL(clf_kernel, dim3(BB), dim3(DT), 0, stream,
                       h2fin, clfwf, clfbf, out);
  } else if (mode12) {
    _Float16* v_all = (_Float16*)((char*)h_base + H_BYTES);
    hipLaunchKernelGGL(vgemm_kernel, dim3(TT), dim3(512), 0, stream,
                       inputs, packB, v_all);
    hipLaunchKernelGGL(rnn12_kernel, dim3(48), dim3(512), 0, stream,
                       inputs, v_all, 1, packB, bfold, csumP, h_base, flags);
    const _Float16* h2fin = h_base + ((size_t)2 * TT + (TT - 1)) * BB * DH;
    hipLaunchKernelGGL(clf_kernel, dim3(BB), dim3(DT), 0, stream,
                       h2fin, clfwf, clfbf, out);
  } else {
    unsigned* arr  = flags;
    unsigned* cons = flags + 1024;
    (void)ring_h_bytes;
    hipLaunchKernelGGL(rnn_ring_kernel, dim3(24), dim3(512), 0, stream,
                       inputs, nullptr, 0, packB, bfold, csumP, h_base, arr, cons);
    const _Float16* h2fin = h_base + (size_t)(2 * RD + ((TT - 1) & (RD - 1))) * BB * DH;
    hipLaunchKernelGGL(clf_kernel, dim3(BB), dim3(DT), 0, stream,
                       h2fin, clfwf, clfbf, out);
  }
}

// Round 14
// 6087.854 us; speedup vs baseline: 1.9798x; 1.9798x over previous
//
#include <hip/hip_runtime.h>

#define DH 512
#define TT 1024
#define BB 64
#define DT 64
#define RD 4   // ring depth (emergency fallback)
#define RG 32  // rows per batch-group

typedef _Float16 f16x8 __attribute__((ext_vector_type(8)));
typedef float f32x4 __attribute__((ext_vector_type(4)));

#define ATILE_HALVES   (64 * 65 * 8)
#define ATILE32_HALVES (64 * 33 * 8)

__device__ __forceinline__ f16x8 cload(const _Float16* p) {
  return *(const volatile f16x8*)p;
}
__device__ __forceinline__ void cstore(_Float16* p, f16x8 v) {
  *(volatile f16x8*)p = v;
}

// ---------------------------------------------------------------- precompute

__global__ __launch_bounds__(512) void eprime_kernel(
    const float* __restrict__ emb, const float* __restrict__ wx0,
    float* __restrict__ Ep)
{
  __shared__ float er[DH];
  const int e = blockIdx.x, j = threadIdx.x;
  er[j] = emb[(size_t)e * DH + j];
  __syncthreads();
  float acc = 0.f;
#pragma unroll 8
  for (int k = 0; k < DH; ++k) acc = fmaf(er[k], wx0[(size_t)k * DH + j], acc);
  Ep[(size_t)e * DH + j] = acc;
}

__global__ __launch_bounds__(512) void pack_kernel(
    const float* __restrict__ Ep, const float* __restrict__ wh0,
    const float* __restrict__ wx1, const float* __restrict__ wh1,
    const float* __restrict__ wx2, const float* __restrict__ wh2,
    const float* __restrict__ gamma, _Float16* __restrict__ dst)
{
  __shared__ float Tt[64][65];
  const int m = blockIdx.z, jt = blockIdx.x, kt = blockIdx.y;
  const float* src = (m == 0) ? Ep : (m == 1) ? wh0 : (m == 2) ? wx1
                   : (m == 3) ? wh1 : (m == 4) ? wx2 : wh2;
  const bool fold = (m == 2 || m == 4);
  const int tx = threadIdx.x & 63, ty = threadIdx.x >> 6;
#pragma unroll
  for (int i = 0; i < 8; ++i) {
    const int k = kt * 64 + ty * 8 + i;
    Tt[ty * 8 + i][tx] = src[(size_t)k * DH + jt * 64 + tx];
  }
  __syncthreads();
#pragma unroll
  for (int i = 0; i < 8; ++i) {
    const int j = jt * 64 + ty * 8 + i;
    const int k = kt * 64 + tx;
    float v = Tt[tx][ty * 8 + i];
    if (fold) v *= gamma[k];
    dst[((size_t)m * DH + j) * DH + k] = (_Float16)v;
  }
}

__global__ __launch_bounds__(512) void fold_kernel(
    const float* __restrict__ b0, const float* __restrict__ b1,
    const float* __restrict__ b2, const float* __restrict__ wx1,
    const float* __restrict__ wx2, const float* __restrict__ gamma,
    const float* __restrict__ beta, const float* __restrict__ clfw,
    const float* __restrict__ clfb,
    float* __restrict__ bfold, float* __restrict__ csum,
    float* __restrict__ clfwf, float* __restrict__ clfbf)
{
  const int j = threadIdx.x;
  if (blockIdx.x == 0) {
    bfold[j] = b0[j];
    float s1 = 0, s2 = 0, c1 = 0, c2 = 0;
    for (int k = 0; k < DH; ++k) {
      const float w1 = wx1[(size_t)k * DH + j], w2 = wx2[(size_t)k * DH + j];
      s1 += beta[k] * w1;  s2 += beta[k] * w2;
      c1 += gamma[k] * w1; c2 += gamma[k] * w2;
    }
    bfold[DH + j] = b1[j] + s1;
    bfold[2 * DH + j] = b2[j] + s2;
    csum[j] = c1; csum[DH + j] = c2;
  } else {
    for (int idx = j; idx < DH * DT; idx += 512) {
      const int k = idx >> 6, d = idx & 63;
      clfwf[idx] = gamma[k] * clfw[(size_t)k * DT + d];
    }
    if (j < DT) {
      float sb = clfb[j];
      for (int k = 0; k < DH; ++k) sb += beta[k] * clfw[(size_t)k * DT + j];
      clfbf[j] = sb;
    }
  }
}

// v_all[t][b][j] (fp16) = sum_e x[b][t][e] * E'[e][j];  one block per t.
__global__ __launch_bounds__(512, 1) void vgemm_kernel(
    const float* __restrict__ x, const _Float16* __restrict__ Bt,
    _Float16* __restrict__ v)
{
  const int t = blockIdx.x;
  const int tid = threadIdx.x, l = tid & 63, w = tid >> 6;
  __shared__ __align__(16) _Float16 A[ATILE_HALVES];
  {
    const int row = tid >> 3, part = tid & 7;
    const float4* sp = (const float4*)(x + ((size_t)row * TT + t) * DH);
#pragma unroll
    for (int i = 0; i < 8; ++i) {
      const int ks = i * 8 + part;
      const float4 a = sp[ks * 2], b = sp[ks * 2 + 1];
      f16x8 vv;
      vv[0] = (_Float16)a.x; vv[1] = (_Float16)a.y; vv[2] = (_Float16)a.z; vv[3] = (_Float16)a.w;
      vv[4] = (_Float16)b.x; vv[5] = (_Float16)b.y; vv[6] = (_Float16)b.z; vv[7] = (_Float16)b.w;
      *(f16x8*)(A + ((size_t)ks * 65 + row) * 8) = vv;
    }
  }
  __syncthreads();
  const int jb = w * 64;
  const int arowb = l & 15, g = l >> 4;
  f32x4 acc[4][4];
#pragma unroll
  for (int mf = 0; mf < 4; ++mf)
#pragma unroll
    for (int nf = 0; nf < 4; ++nf)
#pragma unroll
      for (int e = 0; e < 4; ++e) acc[mf][nf][e] = 0.f;
#pragma unroll
  for (int kk = 0; kk < 16; ++kk) {
    const int ks = kk * 4 + g;
    f16x8 am[4], bn[4];
#pragma unroll
    for (int mf = 0; mf < 4; ++mf)
      am[mf] = *(const f16x8*)(A + ((size_t)ks * 65 + mf * 16 + arowb) * 8);
#pragma unroll
    for (int nf = 0; nf < 4; ++nf)
      bn[nf] = *(const f16x8*)(Bt + (size_t)(jb + nf * 16 + arowb) * DH + kk * 32 + g * 8);
#pragma unroll
    for (int mf = 0; mf < 4; ++mf)
#pragma unroll
      for (int nf = 0; nf < 4; ++nf)
        acc[mf][nf] = __builtin_amdgcn_mfma_f32_16x16x32_f16(am[mf], bn[nf], acc[mf][nf], 0, 0, 0);
  }
#pragma unroll
  for (int mf = 0; mf < 4; ++mf)
#pragma unroll
    for (int nf = 0; nf < 4; ++nf)
#pragma unroll
      for (int i = 0; i < 4; ++i) {
        const int r = mf * 16 + (l >> 4) * 4 + i;
        const int j = jb + nf * 16 + (l & 15);
        v[((size_t)t * BB + r) * DH + j] = (_Float16)acc[mf][nf][i];
      }
}

// ---------------------------------------------------------------- staging

__device__ __forceinline__ void stage_h32(_Float16* __restrict__ A,
                                          const _Float16* __restrict__ src64,
                                          int rbase, float* muA, float* rsA,
                                          bool stats, int tid)
{
  const int row = tid >> 4, part = tid & 15;
  const _Float16* sp = src64 + (size_t)(rbase + row) * DH;
  f16x8 v[4];
#pragma unroll
  for (int i = 0; i < 4; ++i) v[i] = cload(sp + (size_t)(i * 16 + part) * 8);
  float sum = 0.f, sq = 0.f;
#pragma unroll
  for (int i = 0; i < 4; ++i) {
    const int ks = i * 16 + part;
    *(f16x8*)(A + ((size_t)ks * 33 + row) * 8) = v[i];
    if (stats) {
#pragma unroll
      for (int e = 0; e < 8; ++e) { const float f = (float)v[i][e]; sum += f; sq += f * f; }
    }
  }
  if (stats) {
    sum += __shfl_xor(sum, 1); sq += __shfl_xor(sq, 1);
    sum += __shfl_xor(sum, 2); sq += __shfl_xor(sq, 2);
    sum += __shfl_xor(sum, 4); sq += __shfl_xor(sq, 4);
    sum += __shfl_xor(sum, 8); sq += __shfl_xor(sq, 8);
    if (part == 0) {
      const float mu = sum * (1.f / DH);
      const float var = sq * (1.f / DH) - mu * mu;
      muA[row] = mu; rsA[row] = rsqrtf(var + 1e-5f);
    }
  }
}

__device__ __forceinline__ void stage_x32(_Float16* __restrict__ A,
                                          const float* __restrict__ inputs,
                                          int rbase, int t, int tid)
{
  const int row = tid >> 4, part = tid & 15;
  const float4* sp = (const float4*)(inputs + ((size_t)(rbase + row) * TT + t) * DH);
#pragma unroll
  for (int i = 0; i < 4; ++i) {
    const int ks = i * 16 + part;
    const float4 a = sp[ks * 2], b = sp[ks * 2 + 1];
    f16x8 vv;
    vv[0] = (_Float16)a.x; vv[1] = (_Float16)a.y; vv[2] = (_Float16)a.z; vv[3] = (_Float16)a.w;
    vv[4] = (_Float16)b.x; vv[5] = (_Float16)b.y; vv[6] = (_Float16)b.z; vv[7] = (_Float16)b.w;
    *(f16x8*)(A + ((size_t)ks * 33 + row) * 8) = vv;
  }
}

__device__ __forceinline__ void stage_h_coh(_Float16* __restrict__ A,
                                            const _Float16* __restrict__ src,
                                            float* muA, float* rsA, bool stats,
                                            int tid)
{
  const int row = tid >> 3, part = tid & 7;
  const _Float16* sp = src + (size_t)row * DH;
  f16x8 v[8];
#pragma unroll
  for (int i = 0; i < 8; ++i) v[i] = cload(sp + (size_t)(i * 8 + part) * 8);
  float sum = 0.f, sq = 0.f;
#pragma unroll
  for (int i = 0; i < 8; ++i) {
    const int ks = i * 8 + part;
    *(f16x8*)(A + ((size_t)ks * 65 + row) * 8) = v[i];
    if (stats) {
#pragma unroll
      for (int e = 0; e < 8; ++e) { const float f = (float)v[i][e]; sum += f; sq += f * f; }
    }
  }
  if (stats) {
    sum += __shfl_xor(sum, 1); sq += __shfl_xor(sq, 1);
    sum += __shfl_xor(sum, 2); sq += __shfl_xor(sq, 2);
    sum += __shfl_xor(sum, 4); sq += __shfl_xor(sq, 4);
    if (part == 0) {
      const float mu = sum * (1.f / DH);
      const float var = sq * (1.f / DH) - mu * mu;
      muA[row] = mu; rsA[row] = rsqrtf(var + 1e-5f);
    }
  }
}

__device__ __forceinline__ void stage_x64(_Float16* __restrict__ A,
                                          const float* __restrict__ inputs,
                                          int t, int tid)
{
  const int row = tid >> 3, part = tid & 7;
  const float4* sp = (const float4*)(inputs + ((size_t)row * TT + t) * DH);
#pragma unroll
  for (int i = 0; i < 8; ++i) {
    const int ks = i * 8 + part;
    const float4 a = sp[ks * 2], b = sp[ks * 2 + 1];
    f16x8 vv;
    vv[0] = (_Float16)a.x; vv[1] = (_Float16)a.y; vv[2] = (_Float16)a.z; vv[3] = (_Float16)a.w;
    vv[4] = (_Float16)b.x; vv[5] = (_Float16)b.y; vv[6] = (_Float16)b.z; vv[7] = (_Float16)b.w;
    *(f16x8*)(A + ((size_t)ks * 65 + row) * 8) = vv;
  }
}

__device__ __forceinline__ void spin_mask(unsigned* p, unsigned tgt) {
  while (true) {
    bool mine = true;
    if (p) mine = (__hip_atomic_load(p, __ATOMIC_RELAXED, __HIP_MEMORY_SCOPE_AGENT) >= tgt);
    if (__all(mine)) break;
    __builtin_amdgcn_s_sleep(1);
  }
}

// ---------------------------------------------------------------- main RNN (r14)

// r12 structure (48 blocks = 3 layers x 2 groups x 8 col-slices) +
// software-pipelined A1: upstream h(t+1) loads issued at end of beat t
// (after observing upstream flag t+2), latency hidden under publish+poll.
__global__ __launch_bounds__(512, 1) void rnn14_kernel(
    const float* __restrict__ inputs, const _Float16* __restrict__ v_all,
    const int use_v, const _Float16* __restrict__ packB,
    const float* __restrict__ bfold, const float* __restrict__ csum,
    _Float16* __restrict__ h_base, unsigned* __restrict__ arr)
{
  const int bid = blockIdx.x;
  const int s = bid >> 4, g2 = (bid >> 3) & 1, c = bid & 7;
  const int rbase = g2 * RG;
  const int tid = threadIdx.x;
  const int l = tid & 63, w = tid >> 6;
  const int mg = w >> 2, ng = w & 3;
  const int row16 = tid >> 4, part16 = tid & 15;

  __shared__ __align__(16) _Float16 A1[ATILE32_HALVES];
  __shared__ __align__(16) _Float16 A2[ATILE32_HALVES];
  __shared__ __align__(16) _Float16 hout[RG][72];
  __shared__ float muS[RG], rsS[RG];

  const bool sx = (s == 0);
  const bool havev = (use_v != 0);
  const bool needX = (!sx || !havev);

  const int colbase = c * 64 + ng * 16 + (l & 15);
  const int kbase = (l >> 4) * 8;
  f16x8 Bx[16], Bh[16];
  {
    const _Float16* ph = packB + ((size_t)(s * 2 + 1) * DH + colbase) * DH + kbase;
#pragma unroll
    for (int kk = 0; kk < 16; ++kk) Bh[kk] = *(const f16x8*)(ph + kk * 32);
  }
  if (needX) {
    const _Float16* px = packB + ((size_t)(s * 2 + 0) * DH + colbase) * DH + kbase;
#pragma unroll
    for (int kk = 0; kk < 16; ++kk) Bx[kk] = *(const f16x8*)(px + kk * 32);
  }

  const float b_j = bfold[s * DH + colbase];
  const float cs_j = (s > 0) ? csum[(s - 1) * DH + colbase] : 0.f;
  const int g = l >> 4;
  const int fbase = (s * 2 + g2) * 8;
  const int ubase = ((s - 1) * 2 + g2) * 8;

  // ---- prologue: prefetch A1 for t=0 (upstream flag >= 1)
  f16x8 a1r[4];
  if (s > 0) {
    if (w == 0) {
      unsigned* p = (l < 8) ? (arr + (ubase + l) * 16) : nullptr;
      spin_mask(p, 1u);
    }
    __syncthreads();
    const _Float16* sp = h_base + ((size_t)(s - 1) * TT) * BB * DH
                         + (size_t)(rbase + row16) * DH;
#pragma unroll
    for (int i = 0; i < 4; ++i) a1r[i] = cload(sp + (size_t)(i * 16 + part16) * 8);
  }

  for (int t = 0; t < TT; ++t) {
    // ---- commit prefetched A1 to LDS + LN stats (registers -> LDS, no wait)
    if (s > 0) {
      float sum = 0.f, sq = 0.f;
#pragma unroll
      for (int i = 0; i < 4; ++i) {
        const int ks = i * 16 + part16;
        *(f16x8*)(A1 + ((size_t)ks * 33 + row16) * 8) = a1r[i];
#pragma unroll
        for (int e = 0; e < 8; ++e) { const float f = (float)a1r[i][e]; sum += f; sq += f * f; }
      }
      sum += __shfl_xor(sum, 1); sq += __shfl_xor(sq, 1);
      sum += __shfl_xor(sum, 2); sq += __shfl_xor(sq, 2);
      sum += __shfl_xor(sum, 4); sq += __shfl_xor(sq, 4);
      sum += __shfl_xor(sum, 8); sq += __shfl_xor(sq, 8);
      if (part16 == 0) {
        const float mu = sum * (1.f / DH);
        const float var = sq * (1.f / DH) - mu * mu;
        muS[row16] = mu; rsS[row16] = rsqrtf(var + 1e-5f);
      }
    }

    // ---- layer-0 v prefetch (plain loads; latency hides under poll)
    _Float16 vp[4];
    if (sx && havev) {
      const _Float16* vb = v_all + (size_t)t * BB * DH + colbase;
      const int rb = rbase + mg * 16 + (l >> 4) * 4;
#pragma unroll
      for (int i = 0; i < 4; ++i) vp[i] = vb[(size_t)(rb + i) * DH];
    } else if (sx && !havev) {
      stage_x32(A1, inputs, rbase, t, tid);
    }

    // ---- own-layer poll
    if (w == 0) {
      unsigned* p = nullptr; unsigned tgt = 0;
      if (l < 8 && t >= 1) { p = arr + (fbase + l) * 16; tgt = (unsigned)t; }
      spin_mask(p, tgt);
    }
    __syncthreads();   // B1: A1 LDS + stats visible; own flags observed

    // ---- stage A2 = own h(t-1)
    if (t >= 1)
      stage_h32(A2, h_base + ((size_t)s * TT + (t - 1)) * BB * DH, rbase,
                nullptr, nullptr, false, tid);
    __syncthreads();   // B2

    // ---- MFMAs
    f32x4 accX, accH;
#pragma unroll
    for (int e = 0; e < 4; ++e) { accX[e] = 0.f; accH[e] = 0.f; }
    const int arow = mg * 16 + (l & 15);
    if (t >= 1) {
#pragma unroll
      for (int kk = 0; kk < 16; ++kk) {
        const int ks = kk * 4 + g;
        const f16x8 aH = *(const f16x8*)(A2 + ((size_t)ks * 33 + arow) * 8);
        accH = __builtin_amdgcn_mfma_f32_16x16x32_f16(aH, Bh[kk], accH, 0, 0, 0);
      }
    }
    if (needX) {
#pragma unroll
      for (int kk = 0; kk < 16; ++kk) {
        const int ks = kk * 4 + g;
        const f16x8 aX = *(const f16x8*)(A1 + ((size_t)ks * 33 + arow) * 8);
        accX = __builtin_amdgcn_mfma_f32_16x16x32_f16(aX, Bx[kk], accX, 0, 0, 0);
      }
    }

    // ---- epilogue
    const int jl = ng * 16 + (l & 15);
#pragma unroll
    for (int i = 0; i < 4; ++i) {
      const int r = mg * 16 + (l >> 4) * 4 + i;
      float p;
      if (sx) {
        const float v0 = havev ? (float)vp[i] : accX[i];
        p = v0 + accH[i] + b_j;
      } else {
        p = rsS[r] * (accX[i] - muS[r] * cs_j) + accH[i] + b_j;
      }
      hout[r][jl] = (_Float16)tanhf(p);
    }
    __syncthreads();   // B3

    // ---- write-through (LLC) writeback
    if (tid < 256) {
      _Float16* dst = h_base + ((size_t)s * TT + t) * BB * DH;
      const int row = tid >> 3, ch = tid & 7;
      const f16x8 hv = *(const f16x8*)(&hout[row][ch * 8]);
      cstore(dst + (size_t)(rbase + row) * DH + c * 64 + ch * 8, hv);
    }
    __syncthreads();   // B4: vmcnt drained -> visible at LLC
    if (tid == 0)
      __hip_atomic_store(arr + (fbase + c) * 16, (unsigned)(t + 1),
                         __ATOMIC_RELAXED, __HIP_MEMORY_SCOPE_AGENT);

    // ---- prefetch next A1 (upstream normally ahead: one-load poll)
    if (s > 0 && t + 1 < TT) {
      if (w == 0) {
        unsigned* p = (l < 8) ? (arr + (ubase + l) * 16) : nullptr;
        spin_mask(p, (unsigned)(t + 2));
      }
      __syncthreads(); // B5
      const _Float16* sp = h_base + ((size_t)(s - 1) * TT + (t + 1)) * BB * DH
                           + (size_t)(rbase + row16) * DH;
#pragma unroll
      for (int i = 0; i < 4; ++i) a1r[i] = cload(sp + (size_t)(i * 16 + part16) * 8);
      // loads complete during next beat's poll; first use is next B1's LDS write
    }
  }
}

// ---------------------------------------------------- r12 fallback (champion)

__global__ __launch_bounds__(512, 1) void rnn12_kernel(
    const float* __restrict__ inputs, const _Float16* __restrict__ v_all,
    const int use_v, const _Float16* __restrict__ packB,
    const float* __restrict__ bfold, const float* __restrict__ csum,
    _Float16* __restrict__ h_base, unsigned* __restrict__ arr)
{
  const int bid = blockIdx.x;
  const int s = bid >> 4, g2 = (bid >> 3) & 1, c = bid & 7;
  const int rbase = g2 * RG;
  const int tid = threadIdx.x;
  const int l = tid & 63, w = tid >> 6;
  const int mg = w >> 2, ng = w & 3;

  __shared__ __align__(16) _Float16 A1[ATILE32_HALVES];
  __shared__ __align__(16) _Float16 A2[ATILE32_HALVES];
  __shared__ __align__(16) _Float16 hout[RG][72];
  __shared__ float muS[RG], rsS[RG];

  const bool sx = (s == 0);
  const bool havev = (use_v != 0);
  const bool needX = (!sx || !havev);

  const int colbase = c * 64 + ng * 16 + (l & 15);
  const int kbase = (l >> 4) * 8;
  f16x8 Bx[16], Bh[16];
  {
    const _Float16* ph = packB + ((size_t)(s * 2 + 1) * DH + colbase) * DH + kbase;
#pragma unroll
    for (int kk = 0; kk < 16; ++kk) Bh[kk] = *(const f16x8*)(ph + kk * 32);
  }
  if (needX) {
    const _Float16* px = packB + ((size_t)(s * 2 + 0) * DH + colbase) * DH + kbase;
#pragma unroll
    for (int kk = 0; kk < 16; ++kk) Bx[kk] = *(const f16x8*)(px + kk * 32);
  }

  const float b_j = bfold[s * DH + colbase];
  const float cs_j = (s > 0) ? csum[(s - 1) * DH + colbase] : 0.f;
  const int g = l >> 4;
  const int fbase = (s * 2 + g2) * 8;
  const int ubase = ((s - 1) * 2 + g2) * 8;

  for (int t = 0; t < TT; ++t) {
    _Float16 vp[4];
    if (sx && havev) {
      const _Float16* vb = v_all + (size_t)t * BB * DH + colbase;
      const int rb = rbase + mg * 16 + (l >> 4) * 4;
#pragma unroll
      for (int i = 0; i < 4; ++i) vp[i] = vb[(size_t)(rb + i) * DH];
    }

    if (w == 0) {
      unsigned* p = nullptr; unsigned tgt = 0;
      if (l < 8 && t >= 1) { p = arr + (fbase + l) * 16; tgt = (unsigned)t; }
      spin_mask(p, tgt);
    }
    __syncthreads();

    if (t >= 1)
      stage_h32(A2, h_base + ((size_t)s * TT + (t - 1)) * BB * DH, rbase,
                nullptr, nullptr, false, tid);
    __syncthreads();

    f32x4 accX, accH;
#pragma unroll
    for (int e = 0; e < 4; ++e) { accX[e] = 0.f; accH[e] = 0.f; }
    const int arow = mg * 16 + (l & 15);
    if (t >= 1) {
#pragma unroll
      for (int kk = 0; kk < 16; ++kk) {
        const int ks = kk * 4 + g;
        const f16x8 aH = *(const f16x8*)(A2 + ((size_t)ks * 33 + arow) * 8);
        accH = __builtin_amdgcn_mfma_f32_16x16x32_f16(aH, Bh[kk], accH, 0, 0, 0);
      }
    }

    if (s > 0) {
      if (w == 0) {
        unsigned* p = (l < 8) ? (arr + (ubase + l) * 16) : nullptr;
        spin_mask(p, (unsigned)(t + 1));
      }
      __syncthreads();
      stage_h32(A1, h_base + ((size_t)(s - 1) * TT + t) * BB * DH, rbase,
                muS, rsS, true, tid);
      __syncthreads();
    } else if (!havev) {
      stage_x32(A1, inputs, rbase, t, tid);
      __syncthreads();
    }

    if (needX) {
#pragma unroll
      for (int kk = 0; kk < 16; ++kk) {
        const int ks = kk * 4 + g;
        const f16x8 aX = *(const f16x8*)(A1 + ((size_t)ks * 33 + arow) * 8);
        accX = __builtin_amdgcn_mfma_f32_16x16x32_f16(aX, Bx[kk], accX, 0, 0, 0);
      }
    }

    const int jl = ng * 16 + (l & 15);
#pragma unroll
    for (int i = 0; i < 4; ++i) {
      const int r = mg * 16 + (l >> 4) * 4 + i;
      float p;
      if (sx) {
        const float v0 = havev ? (float)vp[i] : accX[i];
        p = v0 + accH[i] + b_j;
      } else {
        p = rsS[r] * (accX[i] - muS[r] * cs_j) + accH[i] + b_j;
      }
      hout[r][jl] = (_Float16)tanhf(p);
    }
    __syncthreads();

    if (tid < 256) {
      _Float16* dst = h_base + ((size_t)s * TT + t) * BB * DH;
      const int row = tid >> 3, ch = tid & 7;
      const f16x8 hv = *(const f16x8*)(&hout[row][ch * 8]);
      cstore(dst + (size_t)(rbase + row) * DH + c * 64 + ch * 8, hv);
    }
    __syncthreads();
    if (tid == 0)
      __hip_atomic_store(arr + (fbase + c) * 16, (unsigned)(t + 1),
                         __ATOMIC_RELAXED, __HIP_MEMORY_SCOPE_AGENT);
  }
}

// ------------------------------------------------- emergency ring fallback

__global__ __launch_bounds__(512, 1) void rnn_ring_kernel(
    const float* __restrict__ inputs, const _Float16* __restrict__ v_all,
    const int use_v, const _Float16* __restrict__ packB,
    const float* __restrict__ bfold, const float* __restrict__ csum,
    _Float16* __restrict__ h_base, unsigned* __restrict__ arr,
    unsigned* __restrict__ cons)
{
  const int bid = blockIdx.x;
  const int s = bid >> 3, c = bid & 7;
  const int tid = threadIdx.x;
  const int l = tid & 63, w = tid >> 6;
  const int mg = w >> 2, ng = w & 3;

  __shared__ __align__(16) _Float16 A1[ATILE_HALVES];
  __shared__ __align__(16) _Float16 A2[ATILE_HALVES];
  __shared__ __align__(16) _Float16 hout[64][72];
  __shared__ float muS[64], rsS[64];

  const bool sx = (s == 0);
  const bool havev = (use_v != 0);
  const bool needX = (!sx || !havev);

  const int colbase = c * 64 + ng * 16 + (l & 15);
  const int kbase = (l >> 4) * 8;
  f16x8 Bx[16], Bh[16];
  {
    const _Float16* ph = packB + ((size_t)(s * 2 + 1) * DH + colbase) * DH + kbase;
#pragma unroll
    for (int kk = 0; kk < 16; ++kk) Bh[kk] = *(const f16x8*)(ph + kk * 32);
  }
  if (needX) {
    const _Float16* px = packB + ((size_t)(s * 2 + 0) * DH + colbase) * DH + kbase;
#pragma unroll
    for (int kk = 0; kk < 16; ++kk) Bx[kk] = *(const f16x8*)(px + kk * 32);
  }

  const float b_j = bfold[s * DH + colbase];
  const float cs_j = (s > 0) ? csum[(s - 1) * DH + colbase] : 0.f;
  const int g = l >> 4;

  for (int t = 0; t < TT; ++t) {
    if (w == 0) {
      unsigned* p = nullptr; unsigned tgt = 0;
      if (l < 8) {
        if (t >= 1) { p = arr + (s * 8 + l) * 16; tgt = (unsigned)t; }
      } else if (l >= 16 && l < 24 && s < 2 && t >= RD) {
        p = cons + (s * 8 + (l - 16)) * 16; tgt = (unsigned)(t - RD + 1);
      }
      spin_mask(p, tgt);
    }
    __syncthreads();
    if (t >= 1)
      stage_h_coh(A2, h_base + (size_t)(s * RD + ((t - 1) & (RD - 1))) * BB * DH,
                  nullptr, nullptr, false, tid);
    __syncthreads();

    f32x4 accX[2], accH[2];
#pragma unroll
    for (int mf = 0; mf < 2; ++mf)
#pragma unroll
      for (int e = 0; e < 4; ++e) { accX[mf][e] = 0.f; accH[mf][e] = 0.f; }

    if (t >= 1) {
#pragma unroll
      for (int kk = 0; kk < 16; ++kk) {
        const int ks = kk * 4 + g;
#pragma unroll
        for (int mf = 0; mf < 2; ++mf) {
          const int arow = mg * 32 + mf * 16 + (l & 15);
          const f16x8 aH = *(const f16x8*)(A2 + ((size_t)ks * 65 + arow) * 8);
          accH[mf] = __builtin_amdgcn_mfma_f32_16x16x32_f16(aH, Bh[kk], accH[mf], 0, 0, 0);
        }
      }
    }

    if (s > 0) {
      if (w == 0) {
        unsigned* p = (l < 8) ? (arr + ((s - 1) * 8 + l) * 16) : nullptr;
        spin_mask(p, (unsigned)(t + 1));
      }
      __syncthreads();
      stage_h_coh(A1, h_base + (size_t)((s - 1) * RD + (t & (RD - 1))) * BB * DH,
                  muS, rsS, true, tid);
      __syncthreads();
      if (tid == 0)
        __hip_atomic_store(cons + ((s - 1) * 8 + c) * 16, (unsigned)(t + 1),
                           __ATOMIC_RELAXED, __HIP_MEMORY_SCOPE_AGENT);
    } else if (!havev) {
      stage_x64(A1, inputs, t, tid);
      __syncthreads();
    }

    if (needX) {
#pragma unroll
      for (int kk = 0; kk < 16; ++kk) {
        const int ks = kk * 4 + g;
#pragma unroll
        for (int mf = 0; mf < 2; ++mf) {
          const int arow = mg * 32 + mf * 16 + (l & 15);
          const f16x8 aX = *(const f16x8*)(A1 + ((size_t)ks * 65 + arow) * 8);
          accX[mf] = __builtin_amdgcn_mfma_f32_16x16x32_f16(aX, Bx[kk], accX[mf], 0, 0, 0);
        }
      }
    }

    const int jl = ng * 16 + (l & 15);
#pragma unroll
    for (int mf = 0; mf < 2; ++mf)
#pragma unroll
      for (int i = 0; i < 4; ++i) {
        const int r = mg * 32 + mf * 16 + (l >> 4) * 4 + i;
        float p;
        if (sx) {
          float v0;
          if (havev) v0 = (float)v_all[((size_t)t * BB + r) * DH + c * 64 + jl];
          else       v0 = accX[mf][i];
          p = v0 + accH[mf][i] + b_j;
        } else {
          p = rsS[r] * (accX[mf][i] - muS[r] * cs_j) + accH[mf][i] + b_j;
        }
        hout[r][jl] = (_Float16)tanhf(p);
      }
    __syncthreads();
    {
      _Float16* dst = h_base + (size_t)(s * RD + (t & (RD - 1))) * BB * DH;
      const int row = tid >> 3, ch = tid & 7;
      const f16x8 hv = *(const f16x8*)(&hout[row][ch * 8]);
      cstore(dst + (size_t)row * DH + c * 64 + ch * 8, hv);
    }
    __syncthreads();
    if (tid == 0)
      __hip_atomic_store(arr + (s * 8 + c) * 16, (unsigned)(t + 1),
                         __ATOMIC_RELAXED, __HIP_MEMORY_SCOPE_AGENT);
  }
}

// ---------------------------------------------------------------- classifier

__global__ __launch_bounds__(64) void clf_kernel(
    const _Float16* __restrict__ h2, const float* __restrict__ clfwf,
    const float* __restrict__ clfbf, float* __restrict__ out)
{
  const int b = blockIdx.x, d = threadIdx.x;
  __shared__ float o2[DH];
  const _Float16* hrow = h2 + (size_t)b * DH;
  float sum = 0.f, sq = 0.f;
#pragma unroll
  for (int i = 0; i < 8; ++i) {
    const float v = (float)hrow[d * 8 + i];
    sum += v; sq += v * v;
  }
#pragma unroll
  for (int off = 32; off; off >>= 1) { sum += __shfl_xor(sum, off); sq += __shfl_xor(sq, off); }
  const float mu = sum * (1.f / DH);
  const float rs = rsqrtf(sq * (1.f / DH) - mu * mu + 1e-5f);
#pragma unroll
  for (int i = 0; i < 8; ++i) o2[d * 8 + i] = ((float)hrow[d * 8 + i] - mu) * rs;
  __syncthreads();
  float acc = clfbf[d];
#pragma unroll 8
  for (int k = 0; k < DH; ++k) acc = fmaf(o2[k], clfwf[k * DT + d], acc);
  float mx = acc;
#pragma unroll
  for (int off = 32; off; off >>= 1) mx = fmaxf(mx, __shfl_xor(mx, off));
  const float e = expf(acc - mx);
  float ss = e;
#pragma unroll
  for (int off = 32; off; off >>= 1) ss += __shfl_xor(ss, off);
  out[(size_t)b * DT + d] = e / ss;
}

// ---------------------------------------------------------------- launch

extern "C" void kernel_launch(void* const* d_in, const int* in_sizes, int n_in,
                              void* d_out, int out_size, void* d_ws, size_t ws_size,
                              hipStream_t stream) {
  const float* inputs = (const float*)d_in[0];
  const float* emb    = (const float*)d_in[1];
  const float* wx0    = (const float*)d_in[2];
  const float* wh0    = (const float*)d_in[3];
  const float* b0     = (const float*)d_in[4];
  const float* wx1    = (const float*)d_in[5];
  const float* wh1    = (const float*)d_in[6];
  const float* b1     = (const float*)d_in[7];
  const float* wx2    = (const float*)d_in[8];
  const float* wh2    = (const float*)d_in[9];
  const float* b2     = (const float*)d_in[10];
  const float* gamma  = (const float*)d_in[11];
  const float* beta   = (const float*)d_in[12];
  const float* clfw   = (const float*)d_in[13];
  const float* clfb   = (const float*)d_in[14];
  float* out = (float*)d_out;

  char* ws = (char*)d_ws;
  size_t off = 0;
  float*    Ep    = (float*)(ws + off);    off += (size_t)DH * DH * 4;
  _Float16* packB = (_Float16*)(ws + off); off += (size_t)6 * DH * DH * 2;
  float*    bfold = (float*)(ws + off);    off += (size_t)3 * DH * 4;
  float*    csumP = (float*)(ws + off);    off += (size_t)2 * DH * 4;
  float*    clfwf = (float*)(ws + off);    off += (size_t)DH * DT * 4;
  float*    clfbf = (float*)(ws + off);    off += 256;
  unsigned* flags = (unsigned*)(ws + off); off += (size_t)2048 * 4;
  off = (off + 255) & ~(size_t)255;
  _Float16* h_base = (_Float16*)(ws + off);

  const size_t H_BYTES = (size_t)3 * TT * BB * DH * 2;   // 192MB
  const size_t V_BYTES = (size_t)TT * BB * DH * 2;       //  64MB

  const int uniq = (ws_size >= off + H_BYTES + V_BYTES) ? 1 : 0;

  (void)hipMemsetAsync(flags, 0, (size_t)2048 * 4, stream);
  hipLaunchKernelGGL(eprime_kernel, dim3(DH), dim3(512), 0, stream, emb, wx0, Ep);
  hipLaunchKernelGGL(pack_kernel, dim3(8, 8, 6), dim3(512), 0, stream,
                     Ep, wh0, wx1, wh1, wx2, wh2, gamma, packB);
  hipLaunchKernelGGL(fold_kernel, dim3(2), dim3(512), 0, stream,
                     b0, b1, b2, wx1, wx2, gamma, beta, clfw, clfb,
                     bfold, csumP, clfwf, clfbf);

  if (uniq) {
    _Float16* v_all = (_Float16*)((char*)h_base + H_BYTES);
    hipLaunchKernelGGL(vgemm_kernel, dim3(TT), dim3(512), 0, stream,
                       inputs, packB, v_all);
    hipLaunchKernelGGL(rnn14_kernel, dim3(48), dim3(512), 0, stream,
                       inputs, v_all, 1, packB, bfold, csumP, h_base, flags);
    const _Float16* h2fin = h_base + ((size_t)2 * TT + (TT - 1)) * BB * DH;
    hipLaunchKernelGGL(clf_kernel, dim3(BB), dim3(DT), 0, stream,
                       h2fin, clfwf, clfbf, out);
  } else {
    unsigned* arr  = flags;
    unsigned* cons = flags + 1024;
    hipLaunchKernelGGL(rnn_ring_kernel, dim3(24), dim3(512), 0, stream,
                       inputs, nullptr, 0, packB, bfold, csumP, h_base, arr, cons);
    const _Float16* h2fin = h_base + (size_t)(2 * RD + ((TT - 1) & (RD - 1))) * BB * DH;
    hipLaunchKernelGGL(clf_kernel, dim3(BB), dim3(DT), 0, stream,
                       h2fin, clfwf, clfbf, out);
  }
}

// Round 15
// 5950.011 us; speedup vs baseline: 2.0256x; 1.0232x over previous
//
#include <hip/hip_runtime.h>

#define DH 512
#define TT 1024
#define BB 64
#define DT 64
#define RD 4   // ring depth (emergency fallback)
#define RG 32  // rows per batch-group

typedef _Float16 f16x8 __attribute__((ext_vector_type(8)));
typedef float f32x4 __attribute__((ext_vector_type(4)));

#define ATILE_HALVES   (64 * 65 * 8)
#define ATILE32_HALVES (64 * 33 * 8)

__device__ __forceinline__ f16x8 cload(const _Float16* p) {
  return *(const volatile f16x8*)p;
}
__device__ __forceinline__ void cstore(_Float16* p, f16x8 v) {
  *(volatile f16x8*)p = v;
}

// ---------------------------------------------------------------- precompute

__global__ __launch_bounds__(512) void eprime_kernel(
    const float* __restrict__ emb, const float* __restrict__ wx0,
    float* __restrict__ Ep)
{
  __shared__ float er[DH];
  const int e = blockIdx.x, j = threadIdx.x;
  er[j] = emb[(size_t)e * DH + j];
  __syncthreads();
  float acc = 0.f;
#pragma unroll 8
  for (int k = 0; k < DH; ++k) acc = fmaf(er[k], wx0[(size_t)k * DH + j], acc);
  Ep[(size_t)e * DH + j] = acc;
}

__global__ __launch_bounds__(512) void pack_kernel(
    const float* __restrict__ Ep, const float* __restrict__ wh0,
    const float* __restrict__ wx1, const float* __restrict__ wh1,
    const float* __restrict__ wx2, const float* __restrict__ wh2,
    const float* __restrict__ gamma, _Float16* __restrict__ dst)
{
  __shared__ float Tt[64][65];
  const int m = blockIdx.z, jt = blockIdx.x, kt = blockIdx.y;
  const float* src = (m == 0) ? Ep : (m == 1) ? wh0 : (m == 2) ? wx1
                   : (m == 3) ? wh1 : (m == 4) ? wx2 : wh2;
  const bool fold = (m == 2 || m == 4);
  const int tx = threadIdx.x & 63, ty = threadIdx.x >> 6;
#pragma unroll
  for (int i = 0; i < 8; ++i) {
    const int k = kt * 64 + ty * 8 + i;
    Tt[ty * 8 + i][tx] = src[(size_t)k * DH + jt * 64 + tx];
  }
  __syncthreads();
#pragma unroll
  for (int i = 0; i < 8; ++i) {
    const int j = jt * 64 + ty * 8 + i;
    const int k = kt * 64 + tx;
    float v = Tt[tx][ty * 8 + i];
    if (fold) v *= gamma[k];
    dst[((size_t)m * DH + j) * DH + k] = (_Float16)v;
  }
}

__global__ __launch_bounds__(512) void fold_kernel(
    const float* __restrict__ b0, const float* __restrict__ b1,
    const float* __restrict__ b2, const float* __restrict__ wx1,
    const float* __restrict__ wx2, const float* __restrict__ gamma,
    const float* __restrict__ beta, const float* __restrict__ clfw,
    const float* __restrict__ clfb,
    float* __restrict__ bfold, float* __restrict__ csum,
    float* __restrict__ clfwf, float* __restrict__ clfbf)
{
  const int j = threadIdx.x;
  if (blockIdx.x == 0) {
    bfold[j] = b0[j];
    float s1 = 0, s2 = 0, c1 = 0, c2 = 0;
    for (int k = 0; k < DH; ++k) {
      const float w1 = wx1[(size_t)k * DH + j], w2 = wx2[(size_t)k * DH + j];
      s1 += beta[k] * w1;  s2 += beta[k] * w2;
      c1 += gamma[k] * w1; c2 += gamma[k] * w2;
    }
    bfold[DH + j] = b1[j] + s1;
    bfold[2 * DH + j] = b2[j] + s2;
    csum[j] = c1; csum[DH + j] = c2;
  } else {
    for (int idx = j; idx < DH * DT; idx += 512) {
      const int k = idx >> 6, d = idx & 63;
      clfwf[idx] = gamma[k] * clfw[(size_t)k * DT + d];
    }
    if (j < DT) {
      float sb = clfb[j];
      for (int k = 0; k < DH; ++k) sb += beta[k] * clfw[(size_t)k * DT + j];
      clfbf[j] = sb;
    }
  }
}

// v_all[t][b][j] (fp16) = sum_e x[b][t][e] * E'[e][j];  one block per t.
__global__ __launch_bounds__(512, 1) void vgemm_kernel(
    const float* __restrict__ x, const _Float16* __restrict__ Bt,
    _Float16* __restrict__ v)
{
  const int t = blockIdx.x;
  const int tid = threadIdx.x, l = tid & 63, w = tid >> 6;
  __shared__ __align__(16) _Float16 A[ATILE_HALVES];
  {
    const int row = tid >> 3, part = tid & 7;
    const float4* sp = (const float4*)(x + ((size_t)row * TT + t) * DH);
#pragma unroll
    for (int i = 0; i < 8; ++i) {
      const int ks = i * 8 + part;
      const float4 a = sp[ks * 2], b = sp[ks * 2 + 1];
      f16x8 vv;
      vv[0] = (_Float16)a.x; vv[1] = (_Float16)a.y; vv[2] = (_Float16)a.z; vv[3] = (_Float16)a.w;
      vv[4] = (_Float16)b.x; vv[5] = (_Float16)b.y; vv[6] = (_Float16)b.z; vv[7] = (_Float16)b.w;
      *(f16x8*)(A + ((size_t)ks * 65 + row) * 8) = vv;
    }
  }
  __syncthreads();
  const int jb = w * 64;
  const int arowb = l & 15, g = l >> 4;
  f32x4 acc[4][4];
#pragma unroll
  for (int mf = 0; mf < 4; ++mf)
#pragma unroll
    for (int nf = 0; nf < 4; ++nf)
#pragma unroll
      for (int e = 0; e < 4; ++e) acc[mf][nf][e] = 0.f;
#pragma unroll
  for (int kk = 0; kk < 16; ++kk) {
    const int ks = kk * 4 + g;
    f16x8 am[4], bn[4];
#pragma unroll
    for (int mf = 0; mf < 4; ++mf)
      am[mf] = *(const f16x8*)(A + ((size_t)ks * 65 + mf * 16 + arowb) * 8);
#pragma unroll
    for (int nf = 0; nf < 4; ++nf)
      bn[nf] = *(const f16x8*)(Bt + (size_t)(jb + nf * 16 + arowb) * DH + kk * 32 + g * 8);
#pragma unroll
    for (int mf = 0; mf < 4; ++mf)
#pragma unroll
      for (int nf = 0; nf < 4; ++nf)
        acc[mf][nf] = __builtin_amdgcn_mfma_f32_16x16x32_f16(am[mf], bn[nf], acc[mf][nf], 0, 0, 0);
  }
#pragma unroll
  for (int mf = 0; mf < 4; ++mf)
#pragma unroll
    for (int nf = 0; nf < 4; ++nf)
#pragma unroll
      for (int i = 0; i < 4; ++i) {
        const int r = mf * 16 + (l >> 4) * 4 + i;
        const int j = jb + nf * 16 + (l & 15);
        v[((size_t)t * BB + r) * DH + j] = (_Float16)acc[mf][nf][i];
      }
}

// ---------------------------------------------------------------- staging

__device__ __forceinline__ void stage_h32(_Float16* __restrict__ A,
                                          const _Float16* __restrict__ src64,
                                          int rbase, float* muA, float* rsA,
                                          bool stats, int tid)
{
  const int row = tid >> 4, part = tid & 15;
  const _Float16* sp = src64 + (size_t)(rbase + row) * DH;
  f16x8 v[4];
#pragma unroll
  for (int i = 0; i < 4; ++i) v[i] = cload(sp + (size_t)(i * 16 + part) * 8);
  float sum = 0.f, sq = 0.f;
#pragma unroll
  for (int i = 0; i < 4; ++i) {
    const int ks = i * 16 + part;
    *(f16x8*)(A + ((size_t)ks * 33 + row) * 8) = v[i];
    if (stats) {
#pragma unroll
      for (int e = 0; e < 8; ++e) { const float f = (float)v[i][e]; sum += f; sq += f * f; }
    }
  }
  if (stats) {
    sum += __shfl_xor(sum, 1); sq += __shfl_xor(sq, 1);
    sum += __shfl_xor(sum, 2); sq += __shfl_xor(sq, 2);
    sum += __shfl_xor(sum, 4); sq += __shfl_xor(sq, 4);
    sum += __shfl_xor(sum, 8); sq += __shfl_xor(sq, 8);
    if (part == 0) {
      const float mu = sum * (1.f / DH);
      const float var = sq * (1.f / DH) - mu * mu;
      muA[row] = mu; rsA[row] = rsqrtf(var + 1e-5f);
    }
  }
}

__device__ __forceinline__ void stage_x32(_Float16* __restrict__ A,
                                          const float* __restrict__ inputs,
                                          int rbase, int t, int tid)
{
  const int row = tid >> 4, part = tid & 15;
  const float4* sp = (const float4*)(inputs + ((size_t)(rbase + row) * TT + t) * DH);
#pragma unroll
  for (int i = 0; i < 4; ++i) {
    const int ks = i * 16 + part;
    const float4 a = sp[ks * 2], b = sp[ks * 2 + 1];
    f16x8 vv;
    vv[0] = (_Float16)a.x; vv[1] = (_Float16)a.y; vv[2] = (_Float16)a.z; vv[3] = (_Float16)a.w;
    vv[4] = (_Float16)b.x; vv[5] = (_Float16)b.y; vv[6] = (_Float16)b.z; vv[7] = (_Float16)b.w;
    *(f16x8*)(A + ((size_t)ks * 33 + row) * 8) = vv;
  }
}

__device__ __forceinline__ void stage_h_coh(_Float16* __restrict__ A,
                                            const _Float16* __restrict__ src,
                                            float* muA, float* rsA, bool stats,
                                            int tid)
{
  const int row = tid >> 3, part = tid & 7;
  const _Float16* sp = src + (size_t)row * DH;
  f16x8 v[8];
#pragma unroll
  for (int i = 0; i < 8; ++i) v[i] = cload(sp + (size_t)(i * 8 + part) * 8);
  float sum = 0.f, sq = 0.f;
#pragma unroll
  for (int i = 0; i < 8; ++i) {
    const int ks = i * 8 + part;
    *(f16x8*)(A + ((size_t)ks * 65 + row) * 8) = v[i];
    if (stats) {
#pragma unroll
      for (int e = 0; e < 8; ++e) { const float f = (float)v[i][e]; sum += f; sq += f * f; }
    }
  }
  if (stats) {
    sum += __shfl_xor(sum, 1); sq += __shfl_xor(sq, 1);
    sum += __shfl_xor(sum, 2); sq += __shfl_xor(sq, 2);
    sum += __shfl_xor(sum, 4); sq += __shfl_xor(sq, 4);
    if (part == 0) {
      const float mu = sum * (1.f / DH);
      const float var = sq * (1.f / DH) - mu * mu;
      muA[row] = mu; rsA[row] = rsqrtf(var + 1e-5f);
    }
  }
}

__device__ __forceinline__ void stage_x64(_Float16* __restrict__ A,
                                          const float* __restrict__ inputs,
                                          int t, int tid)
{
  const int row = tid >> 3, part = tid & 7;
  const float4* sp = (const float4*)(inputs + ((size_t)row * TT + t) * DH);
#pragma unroll
  for (int i = 0; i < 8; ++i) {
    const int ks = i * 8 + part;
    const float4 a = sp[ks * 2], b = sp[ks * 2 + 1];
    f16x8 vv;
    vv[0] = (_Float16)a.x; vv[1] = (_Float16)a.y; vv[2] = (_Float16)a.z; vv[3] = (_Float16)a.w;
    vv[4] = (_Float16)b.x; vv[5] = (_Float16)b.y; vv[6] = (_Float16)b.z; vv[7] = (_Float16)b.w;
    *(f16x8*)(A + ((size_t)ks * 65 + row) * 8) = vv;
  }
}

__device__ __forceinline__ void spin_mask(unsigned* p, unsigned tgt) {
  while (true) {
    bool mine = true;
    if (p) mine = (__hip_atomic_load(p, __ATOMIC_RELAXED, __HIP_MEMORY_SCOPE_AGENT) >= tgt);
    if (__all(mine)) break;
    __builtin_amdgcn_s_sleep(1);
  }
}

// ---------------------------------------------------------------- main RNN (r15)

// r14 + two in-beat overlaps: (1) A2 LLC loads issued before accX, committed
// to LDS after (latency hidden under MFMA); (2) upstream t+2 poll runs while
// writeback stores drain (single barrier covers both). Protocol unchanged.
__global__ __launch_bounds__(512, 1) void rnn15_kernel(
    const float* __restrict__ inputs, const _Float16* __restrict__ v_all,
    const int use_v, const _Float16* __restrict__ packB,
    const float* __restrict__ bfold, const float* __restrict__ csum,
    _Float16* __restrict__ h_base, unsigned* __restrict__ arr)
{
  const int bid = blockIdx.x;
  const int s = bid >> 4, g2 = (bid >> 3) & 1, c = bid & 7;
  const int rbase = g2 * RG;
  const int tid = threadIdx.x;
  const int l = tid & 63, w = tid >> 6;
  const int mg = w >> 2, ng = w & 3;
  const int row16 = tid >> 4, part16 = tid & 15;

  __shared__ __align__(16) _Float16 A1[ATILE32_HALVES];
  __shared__ __align__(16) _Float16 A2[ATILE32_HALVES];
  __shared__ __align__(16) _Float16 hout[RG][72];
  __shared__ float muS[RG], rsS[RG];

  const bool sx = (s == 0);
  const bool havev = (use_v != 0);
  const bool needX = (!sx || !havev);

  const int colbase = c * 64 + ng * 16 + (l & 15);
  const int kbase = (l >> 4) * 8;
  f16x8 Bx[16], Bh[16];
  {
    const _Float16* ph = packB + ((size_t)(s * 2 + 1) * DH + colbase) * DH + kbase;
#pragma unroll
    for (int kk = 0; kk < 16; ++kk) Bh[kk] = *(const f16x8*)(ph + kk * 32);
  }
  if (needX) {
    const _Float16* px = packB + ((size_t)(s * 2 + 0) * DH + colbase) * DH + kbase;
#pragma unroll
    for (int kk = 0; kk < 16; ++kk) Bx[kk] = *(const f16x8*)(px + kk * 32);
  }

  const float b_j = bfold[s * DH + colbase];
  const float cs_j = (s > 0) ? csum[(s - 1) * DH + colbase] : 0.f;
  const int g = l >> 4;
  const int fbase = (s * 2 + g2) * 8;
  const int ubase = ((s - 1) * 2 + g2) * 8;

  // ---- prologue: prefetch A1 for t=0 (upstream flag >= 1)
  f16x8 a1r[4];
  if (s > 0) {
    if (w == 0) {
      unsigned* p = (l < 8) ? (arr + (ubase + l) * 16) : nullptr;
      spin_mask(p, 1u);
    }
    __syncthreads();
    const _Float16* sp = h_base + ((size_t)(s - 1) * TT) * BB * DH
                         + (size_t)(rbase + row16) * DH;
#pragma unroll
    for (int i = 0; i < 4; ++i) a1r[i] = cload(sp + (size_t)(i * 16 + part16) * 8);
  }

  for (int t = 0; t < TT; ++t) {
    // ---- commit prefetched A1 to LDS + LN stats
    if (s > 0) {
      float sum = 0.f, sq = 0.f;
#pragma unroll
      for (int i = 0; i < 4; ++i) {
        const int ks = i * 16 + part16;
        *(f16x8*)(A1 + ((size_t)ks * 33 + row16) * 8) = a1r[i];
#pragma unroll
        for (int e = 0; e < 8; ++e) { const float f = (float)a1r[i][e]; sum += f; sq += f * f; }
      }
      sum += __shfl_xor(sum, 1); sq += __shfl_xor(sq, 1);
      sum += __shfl_xor(sum, 2); sq += __shfl_xor(sq, 2);
      sum += __shfl_xor(sum, 4); sq += __shfl_xor(sq, 4);
      sum += __shfl_xor(sum, 8); sq += __shfl_xor(sq, 8);
      if (part16 == 0) {
        const float mu = sum * (1.f / DH);
        const float var = sq * (1.f / DH) - mu * mu;
        muS[row16] = mu; rsS[row16] = rsqrtf(var + 1e-5f);
      }
    }

    // ---- layer-0 v prefetch / x staging
    _Float16 vp[4];
    if (sx && havev) {
      const _Float16* vb = v_all + (size_t)t * BB * DH + colbase;
      const int rb = rbase + mg * 16 + (l >> 4) * 4;
#pragma unroll
      for (int i = 0; i < 4; ++i) vp[i] = vb[(size_t)(rb + i) * DH];
    } else if (sx && !havev) {
      stage_x32(A1, inputs, rbase, t, tid);
    }

    // ---- own-layer poll
    if (w == 0) {
      unsigned* p = nullptr; unsigned tgt = 0;
      if (l < 8 && t >= 1) { p = arr + (fbase + l) * 16; tgt = (unsigned)t; }
      spin_mask(p, tgt);
    }
    __syncthreads();   // B1: A1 in LDS; own flags observed

    // ---- issue A2 loads (no wait yet)
    f16x8 a2r[4];
    if (t >= 1) {
      const _Float16* sp = h_base + ((size_t)s * TT + (t - 1)) * BB * DH
                           + (size_t)(rbase + row16) * DH;
#pragma unroll
      for (int i = 0; i < 4; ++i) a2r[i] = cload(sp + (size_t)(i * 16 + part16) * 8);
    }

    // ---- accX while A2 is in flight
    f32x4 accX, accH;
#pragma unroll
    for (int e = 0; e < 4; ++e) { accX[e] = 0.f; accH[e] = 0.f; }
    const int arow = mg * 16 + (l & 15);
    if (needX) {
#pragma unroll
      for (int kk = 0; kk < 16; ++kk) {
        const int ks = kk * 4 + g;
        const f16x8 aX = *(const f16x8*)(A1 + ((size_t)ks * 33 + arow) * 8);
        accX = __builtin_amdgcn_mfma_f32_16x16x32_f16(aX, Bx[kk], accX, 0, 0, 0);
      }
    }

    // ---- commit A2 -> LDS (vmcnt wait lands here, after the MFMAs)
    if (t >= 1) {
#pragma unroll
      for (int i = 0; i < 4; ++i)
        *(f16x8*)(A2 + ((size_t)(i * 16 + part16) * 33 + row16) * 8) = a2r[i];
    }
    __syncthreads();   // B2

    // ---- accH
    if (t >= 1) {
#pragma unroll
      for (int kk = 0; kk < 16; ++kk) {
        const int ks = kk * 4 + g;
        const f16x8 aH = *(const f16x8*)(A2 + ((size_t)ks * 33 + arow) * 8);
        accH = __builtin_amdgcn_mfma_f32_16x16x32_f16(aH, Bh[kk], accH, 0, 0, 0);
      }
    }

    // ---- epilogue
    const int jl = ng * 16 + (l & 15);
#pragma unroll
    for (int i = 0; i < 4; ++i) {
      const int r = mg * 16 + (l >> 4) * 4 + i;
      float p;
      if (sx) {
        const float v0 = havev ? (float)vp[i] : accX[i];
        p = v0 + accH[i] + b_j;
      } else {
        p = rsS[r] * (accX[i] - muS[r] * cs_j) + accH[i] + b_j;
      }
      hout[r][jl] = (_Float16)tanhf(p);
    }
    __syncthreads();   // B3

    // ---- writeback stores issued; upstream t+2 poll overlaps the drain
    if (tid < 256) {
      _Float16* dst = h_base + ((size_t)s * TT + t) * BB * DH;
      const int row = tid >> 3, ch = tid & 7;
      const f16x8 hv = *(const f16x8*)(&hout[row][ch * 8]);
      cstore(dst + (size_t)(rbase + row) * DH + c * 64 + ch * 8, hv);
    }
    if (s > 0 && t + 1 < TT) {
      if (w == 0) {
        unsigned* p = (l < 8) ? (arr + (ubase + l) * 16) : nullptr;
        spin_mask(p, (unsigned)(t + 2));
      }
    }
    __syncthreads();   // B4: drains writeback stores; poll result published
    if (tid == 0)
      __hip_atomic_store(arr + (fbase + c) * 16, (unsigned)(t + 1),
                         __ATOMIC_RELAXED, __HIP_MEMORY_SCOPE_AGENT);

    // ---- A1 prefetch for t+1 (waits at next beat's commit, free latency)
    if (s > 0 && t + 1 < TT) {
      const _Float16* sp = h_base + ((size_t)(s - 1) * TT + (t + 1)) * BB * DH
                           + (size_t)(rbase + row16) * DH;
#pragma unroll
      for (int i = 0; i < 4; ++i) a1r[i] = cload(sp + (size_t)(i * 16 + part16) * 8);
    }
  }
}

// ------------------------------------------------- emergency ring fallback

__global__ __launch_bounds__(512, 1) void rnn_ring_kernel(
    const float* __restrict__ inputs, const _Float16* __restrict__ v_all,
    const int use_v, const _Float16* __restrict__ packB,
    const float* __restrict__ bfold, const float* __restrict__ csum,
    _Float16* __restrict__ h_base, unsigned* __restrict__ arr,
    unsigned* __restrict__ cons)
{
  const int bid = blockIdx.x;
  const int s = bid >> 3, c = bid & 7;
  const int tid = threadIdx.x;
  const int l = tid & 63, w = tid >> 6;
  const int mg = w >> 2, ng = w & 3;

  __shared__ __align__(16) _Float16 A1[ATILE_HALVES];
  __shared__ __align__(16) _Float16 A2[ATILE_HALVES];
  __shared__ __align__(16) _Float16 hout[64][72];
  __shared__ float muS[64], rsS[64];

  const bool sx = (s == 0);
  const bool havev = (use_v != 0);
  const bool needX = (!sx || !havev);

  const int colbase = c * 64 + ng * 16 + (l & 15);
  const int kbase = (l >> 4) * 8;
  f16x8 Bx[16], Bh[16];
  {
    const _Float16* ph = packB + ((size_t)(s * 2 + 1) * DH + colbase) * DH + kbase;
#pragma unroll
    for (int kk = 0; kk < 16; ++kk) Bh[kk] = *(const f16x8*)(ph + kk * 32);
  }
  if (needX) {
    const _Float16* px = packB + ((size_t)(s * 2 + 0) * DH + colbase) * DH + kbase;
#pragma unroll
    for (int kk = 0; kk < 16; ++kk) Bx[kk] = *(const f16x8*)(px + kk * 32);
  }

  const float b_j = bfold[s * DH + colbase];
  const float cs_j = (s > 0) ? csum[(s - 1) * DH + colbase] : 0.f;
  const int g = l >> 4;

  for (int t = 0; t < TT; ++t) {
    if (w == 0) {
      unsigned* p = nullptr; unsigned tgt = 0;
      if (l < 8) {
        if (t >= 1) { p = arr + (s * 8 + l) * 16; tgt = (unsigned)t; }
      } else if (l >= 16 && l < 24 && s < 2 && t >= RD) {
        p = cons + (s * 8 + (l - 16)) * 16; tgt = (unsigned)(t - RD + 1);
      }
      spin_mask(p, tgt);
    }
    __syncthreads();
    if (t >= 1)
      stage_h_coh(A2, h_base + (size_t)(s * RD + ((t - 1) & (RD - 1))) * BB * DH,
                  nullptr, nullptr, false, tid);
    __syncthreads();

    f32x4 accX[2], accH[2];
#pragma unroll
    for (int mf = 0; mf < 2; ++mf)
#pragma unroll
      for (int e = 0; e < 4; ++e) { accX[mf][e] = 0.f; accH[mf][e] = 0.f; }

    if (t >= 1) {
#pragma unroll
      for (int kk = 0; kk < 16; ++kk) {
        const int ks = kk * 4 + g;
#pragma unroll
        for (int mf = 0; mf < 2; ++mf) {
          const int arow = mg * 32 + mf * 16 + (l & 15);
          const f16x8 aH = *(const f16x8*)(A2 + ((size_t)ks * 65 + arow) * 8);
          accH[mf] = __builtin_amdgcn_mfma_f32_16x16x32_f16(aH, Bh[kk], accH[mf], 0, 0, 0);
        }
      }
    }

    if (s > 0) {
      if (w == 0) {
        unsigned* p = (l < 8) ? (arr + ((s - 1) * 8 + l) * 16) : nullptr;
        spin_mask(p, (unsigned)(t + 1));
      }
      __syncthreads();
      stage_h_coh(A1, h_base + (size_t)((s - 1) * RD + (t & (RD - 1))) * BB * DH,
                  muS, rsS, true, tid);
      __syncthreads();
      if (tid == 0)
        __hip_atomic_store(cons + ((s - 1) * 8 + c) * 16, (unsigned)(t + 1),
                           __ATOMIC_RELAXED, __HIP_MEMORY_SCOPE_AGENT);
    } else if (!havev) {
      stage_x64(A1, inputs, t, tid);
      __syncthreads();
    }

    if (needX) {
#pragma unroll
      for (int kk = 0; kk < 16; ++kk) {
        const int ks = kk * 4 + g;
#pragma unroll
        for (int mf = 0; mf < 2; ++mf) {
          const int arow = mg * 32 + mf * 16 + (l & 15);
          const f16x8 aX = *(const f16x8*)(A1 + ((size_t)ks * 65 + arow) * 8);
          accX[mf] = __builtin_amdgcn_mfma_f32_16x16x32_f16(aX, Bx[kk], accX[mf], 0, 0, 0);
        }
      }
    }

    const int jl = ng * 16 + (l & 15);
#pragma unroll
    for (int mf = 0; mf < 2; ++mf)
#pragma unroll
      for (int i = 0; i < 4; ++i) {
        const int r = mg * 32 + mf * 16 + (l >> 4) * 4 + i;
        float p;
        if (sx) {
          float v0;
          if (havev) v0 = (float)v_all[((size_t)t * BB + r) * DH + c * 64 + jl];
          else       v0 = accX[mf][i];
          p = v0 + accH[mf][i] + b_j;
        } else {
          p = rsS[r] * (accX[mf][i] - muS[r] * cs_j) + accH[mf][i] + b_j;
        }
        hout[r][jl] = (_Float16)tanhf(p);
      }
    __syncthreads();
    {
      _Float16* dst = h_base + (size_t)(s * RD + (t & (RD - 1))) * BB * DH;
      const int row = tid >> 3, ch = tid & 7;
      const f16x8 hv = *(const f16x8*)(&hout[row][ch * 8]);
      cstore(dst + (size_t)row * DH + c * 64 + ch * 8, hv);
    }
    __syncthreads();
    if (tid == 0)
      __hip_atomic_store(arr + (s * 8 + c) * 16, (unsigned)(t + 1),
                         __ATOMIC_RELAXED, __HIP_MEMORY_SCOPE_AGENT);
  }
}

// ---------------------------------------------------------------- classifier

__global__ __launch_bounds__(64) void clf_kernel(
    const _Float16* __restrict__ h2, const float* __restrict__ clfwf,
    const float* __restrict__ clfbf, float* __restrict__ out)
{
  const int b = blockIdx.x, d = threadIdx.x;
  __shared__ float o2[DH];
  const _Float16* hrow = h2 + (size_t)b * DH;
  float sum = 0.f, sq = 0.f;
#pragma unroll
  for (int i = 0; i < 8; ++i) {
    const float v = (float)hrow[d * 8 + i];
    sum += v; sq += v * v;
  }
#pragma unroll
  for (int off = 32; off; off >>= 1) { sum += __shfl_xor(sum, off); sq += __shfl_xor(sq, off); }
  const float mu = sum * (1.f / DH);
  const float rs = rsqrtf(sq * (1.f / DH) - mu * mu + 1e-5f);
#pragma unroll
  for (int i = 0; i < 8; ++i) o2[d * 8 + i] = ((float)hrow[d * 8 + i] - mu) * rs;
  __syncthreads();
  float acc = clfbf[d];
#pragma unroll 8
  for (int k = 0; k < DH; ++k) acc = fmaf(o2[k], clfwf[k * DT + d], acc);
  float mx = acc;
#pragma unroll
  for (int off = 32; off; off >>= 1) mx = fmaxf(mx, __shfl_xor(mx, off));
  const float e = expf(acc - mx);
  float ss = e;
#pragma unroll
  for (int off = 32; off; off >>= 1) ss += __shfl_xor(ss, off);
  out[(size_t)b * DT + d] = e / ss;
}

// ---------------------------------------------------------------- launch

extern "C" void kernel_launch(void* const* d_in, const int* in_sizes, int n_in,
                              void* d_out, int out_size, void* d_ws, size_t ws_size,
                              hipStream_t stream) {
  const float* inputs = (const float*)d_in[0];
  const float* emb    = (const float*)d_in[1];
  const float* wx0    = (const float*)d_in[2];
  const float* wh0    = (const float*)d_in[3];
  const float* b0     = (const float*)d_in[4];
  const float* wx1    = (const float*)d_in[5];
  const float* wh1    = (const float*)d_in[6];
  const float* b1     = (const float*)d_in[7];
  const float* wx2    = (const float*)d_in[8];
  const float* wh2    = (const float*)d_in[9];
  const float* b2     = (const float*)d_in[10];
  const float* gamma  = (const float*)d_in[11];
  const float* beta   = (const float*)d_in[12];
  const float* clfw   = (const float*)d_in[13];
  const float* clfb   = (const float*)d_in[14];
  float* out = (float*)d_out;

  char* ws = (char*)d_ws;
  size_t off = 0;
  float*    Ep    = (float*)(ws + off);    off += (size_t)DH * DH * 4;
  _Float16* packB = (_Float16*)(ws + off); off += (size_t)6 * DH * DH * 2;
  float*    bfold = (float*)(ws + off);    off += (size_t)3 * DH * 4;
  float*    csumP = (float*)(ws + off);    off += (size_t)2 * DH * 4;
  float*    clfwf = (float*)(ws + off);    off += (size_t)DH * DT * 4;
  float*    clfbf = (float*)(ws + off);    off += 256;
  unsigned* flags = (unsigned*)(ws + off); off += (size_t)2048 * 4;
  off = (off + 255) & ~(size_t)255;
  _Float16* h_base = (_Float16*)(ws + off);

  const size_t H_BYTES = (size_t)3 * TT * BB * DH * 2;   // 192MB
  const size_t V_BYTES = (size_t)TT * BB * DH * 2;       //  64MB

  const int uniq = (ws_size >= off + H_BYTES + V_BYTES) ? 1 : 0;

  (void)hipMemsetAsync(flags, 0, (size_t)2048 * 4, stream);
  hipLaunchKernelGGL(eprime_kernel, dim3(DH), dim3(512), 0, stream, emb, wx0, Ep);
  hipLaunchKernelGGL(pack_kernel, dim3(8, 8, 6), dim3(512), 0, stream,
                     Ep, wh0, wx1, wh1, wx2, wh2, gamma, packB);
  hipLaunchKernelGGL(fold_kernel, dim3(2), dim3(512), 0, stream,
                     b0, b1, b2, wx1, wx2, gamma, beta, clfw, clfb,
                     bfold, csumP, clfwf, clfbf);

  if (uniq) {
    _Float16* v_all = (_Float16*)((char*)h_base + H_BYTES);
    hipLaunchKernelGGL(vgemm_kernel, dim3(TT), dim3(512), 0, stream,
                       inputs, packB, v_all);
    hipLaunchKernelGGL(rnn15_kernel, dim3(48), dim3(512), 0, stream,
                       inputs, v_all, 1, packB, bfold, csumP, h_base, flags);
    const _Float16* h2fin = h_base + ((size_t)2 * TT + (TT - 1)) * BB * DH;
    hipLaunchKernelGGL(clf_kernel, dim3(BB), dim3(DT), 0, stream,
                       h2fin, clfwf, clfbf, out);
  } else {
    unsigned* arr  = flags;
    unsigned* cons = flags + 1024;
    hipLaunchKernelGGL(rnn_ring_kernel, dim3(24), dim3(512), 0, stream,
                       inputs, nullptr, 0, packB, bfold, csumP, h_base, arr, cons);
    const _Float16* h2fin = h_base + (size_t)(2 * RD + ((TT - 1) & (RD - 1))) * BB * DH;
    hipLaunchKernelGGL(clf_kernel, dim3(BB), dim3(DT), 0, stream,
                       h2fin, clfwf, clfbf, out);
  }
}